// Round 1
// baseline (436.278 us; speedup 1.0000x reference)
//
#include <hip/hip_runtime.h>
#include <hip/hip_fp16.h>

// FlashACE: 2-layer edge-MLP message passing + node update, N=50000, E=1.6M, HID=128.
//   Xs = S@w1[0:128], Xrb = S@w1[128:256] + b1          (MFMA f16 GEMMs, B direct-global)
//   P[r] = sum_e silu(Xs[s_e] + Xrb[r] + len_e*w1[256]) (edge pass over CSR, scalar path)
//   S += P@w2 + deg*b2 ; out = S + MLP(S)               (MFMA f16 GEMMs)
// Round 11 = Round 10 with a restructured k_edge:
//   * masked final block replaces mid-block + scalar tail (no per-edge serial
//     gather->use stalls; clamped duplicate gathers are L1 hits, contributions
//     zeroed via fp16 mask folded into the accumulate fma)
//   * 2 receivers per wave; both rows' first-block payloads+gathers issued up
//     front so row1's prologue latency hides under row0's compute.

#define NFEAT 224
#define RBITS 8                 // receivers per bucket = 256
#define NB 196                  // ceil(50000/256)
#define CAP 10240               // bucket region capacity (mean 8163, sigma ~90)

typedef _Float16 v8h __attribute__((ext_vector_type(8)));
typedef _Float16 v2h __attribute__((ext_vector_type(2)));
typedef float f32x4 __attribute__((ext_vector_type(4)));

#define MFMA16(a, b, c) __builtin_amdgcn_mfma_f32_16x16x32_f16(a, b, c, 0, 0, 0)

__device__ __forceinline__ float silu_f(float x) {
    float e = __expf(-x);
    return x * __builtin_amdgcn_rcpf(1.0f + e);
}

// ---------------- prep: blocks 0..7 pack weights; rest copy h rest-cols -> out
__global__ void k_prep(const float* __restrict__ mp_w1, const float* __restrict__ mp_w2,
                       const float* __restrict__ nu_w1, const float* __restrict__ nu_w2,
                       _Float16* __restrict__ Wp,
                       const float4* __restrict__ h4, float4* __restrict__ out4, int N) {
    if (blockIdx.x < 8) {
        const float* srcs[8] = {
            mp_w1, mp_w1 + 16384, mp_w2,
            mp_w1 + 32896, mp_w1 + 32896 + 16384, mp_w2 + 16384,
            nu_w1, nu_w2
        };
        const float* W = srcs[blockIdx.x];
        _Float16* dst = Wp + (size_t)blockIdx.x * 16384;
        for (int i = 0; i < 8; ++i) {
            int u = threadIdx.x + i * 256;
            int nt = u >> 8;
            int kt = (u >> 6) & 3;
            int lane = u & 63;
            int kb = kt * 32 + (lane >> 4) * 8;
            int n = nt * 16 + (lane & 15);
#pragma unroll
            for (int j = 0; j < 8; ++j)
                dst[(size_t)u * 8 + j] = (_Float16)W[(size_t)(kb + j) * 128 + n];
        }
    } else {
        int b = blockIdx.x - 8;
        int t = threadIdx.x;
        if (t < 240) {
            int r = b * 10 + t / 24;
            int c = t % 24;
            if (r < N) out4[(size_t)r * 56 + 32 + c] = h4[(size_t)r * 56 + 32 + c];
        }
    }
}

// ---------------- counting sort pass 1: scatter edges into over-allocated buckets
__global__ void cs_bucket(const int* __restrict__ recv, const int* __restrict__ sender,
                          const float* __restrict__ elen, int* __restrict__ cnt,
                          int* __restrict__ br, unsigned* __restrict__ bsl,
                          int E, int chunk) {
    __shared__ int lhist[256];
    __shared__ int lcur[256];
    int t = threadIdx.x;
    int start = blockIdx.x * chunk;
    int end = start + chunk; if (end > E) end = E;
    lhist[t] = 0;
    __syncthreads();
    for (int i = start + t; i < end; i += 256)
        atomicAdd(&lhist[recv[i] >> RBITS], 1);
    __syncthreads();
    if (t < NB) {
        int c = lhist[t];
        lcur[t] = t * CAP + (c ? atomicAdd(&cnt[t], c) : 0);
    }
    __syncthreads();
    for (int i = start + t; i < end; i += 256) {
        int r = recv[i];
        int pos = atomicAdd(&lcur[r >> RBITS], 1);
        br[pos] = r;
        bsl[pos] = (unsigned)sender[i] |
                   ((unsigned)__half_as_ushort(__float2half_rn(elen[i])) << 16);
    }
}

// ---------------- counting sort pass 2: one wg per bucket -> CSR + deg/rowstart
__global__ void cs_csr(const int* __restrict__ cnt, const int* __restrict__ br,
                       const unsigned* __restrict__ bsl,
                       int* __restrict__ deg, int* __restrict__ rowstart,
                       unsigned* __restrict__ epack, int N) {
    __shared__ int hist[256];
    __shared__ int sh[256];
    __shared__ int lcur[256];
    int t = threadIdx.x;
    int b = blockIdx.x;
    int r0 = b << RBITS;
    int e0 = b * CAP;
    int e1 = e0 + cnt[b];
    hist[t] = 0;
    __syncthreads();
    for (int i = e0 + t; i < e1; i += 256)
        atomicAdd(&hist[br[i] & 255], 1);
    __syncthreads();
    sh[t] = hist[t];
    __syncthreads();
    for (int off = 1; off < 256; off <<= 1) {
        int add = (t >= off) ? sh[t - off] : 0;
        __syncthreads();
        sh[t] += add;
        __syncthreads();
    }
    int excl = (t == 0) ? 0 : sh[t - 1];
    lcur[t] = e0 + excl;
    int r = r0 + t;
    if (r < N) { deg[r] = hist[t]; rowstart[r] = e0 + excl; }
    __syncthreads();
    for (int i = e0 + t; i < e1; i += 256) {
        int rr = br[i];
        int pos = atomicAdd(&lcur[rr & 255], 1);
        epack[pos] = bsl[i];
    }
}

// ================ MFMA GEMM core: M-tile 64, N=K=128, 256 thr (4 waves) ================
// A staged via LDS. B fragments load DIRECTLY from global (coalesced, L2-hot).

#define MM_STAGE_A_F32(Aptr, ldA)                                           \
    _Pragma("unroll") for (int i = 0; i < 4; ++i) {                         \
        int u = threadIdx.x + i * 256;                                      \
        int r = u >> 4;                                                     \
        int g = u & 15;                                                     \
        int gr = blockIdx.x * 64 + r;                                       \
        float4 x0 = make_float4(0.f, 0.f, 0.f, 0.f);                        \
        float4 x1 = x0;                                                     \
        if (gr < M) {                                                       \
            const float* s_ = (Aptr) + (size_t)gr * (ldA) + g * 8;          \
            x0 = *(const float4*)s_;                                        \
            x1 = *(const float4*)(s_ + 4);                                  \
        }                                                                   \
        v8h hv;                                                             \
        hv[0] = (_Float16)x0.x; hv[1] = (_Float16)x0.y;                     \
        hv[2] = (_Float16)x0.z; hv[3] = (_Float16)x0.w;                     \
        hv[4] = (_Float16)x1.x; hv[5] = (_Float16)x1.y;                     \
        hv[6] = (_Float16)x1.z; hv[7] = (_Float16)x1.w;                     \
        Af[((r >> 4) * 4 + (g >> 2)) * 64 + (g & 3) * 16 + (r & 15)] = hv;  \
    }

#define MM_STAGE_A_F16(Aptr)                                                \
    _Pragma("unroll") for (int i = 0; i < 4; ++i) {                         \
        int u = threadIdx.x + i * 256;                                      \
        int r = u >> 4;                                                     \
        int g = u & 15;                                                     \
        int gr = blockIdx.x * 64 + r;                                       \
        float4 x = make_float4(0.f, 0.f, 0.f, 0.f);                         \
        if (gr < M) x = *(const float4*)((Aptr) + (size_t)gr * 128 + g * 8);\
        *(float4*)&Af[((r >> 4) * 4 + (g >> 2)) * 64 + (g & 3) * 16 + (r & 15)] = x; \
    }

#define MM_WAVE_PROLOG                                                      \
    __syncthreads();                                                        \
    const int wv = threadIdx.x >> 6;                                        \
    const int lane = threadIdx.x & 63;                                      \
    const int q_ = lane >> 4;                                               \
    const int c0_ = lane & 15;                                              \
    v8h a0 = Af[(wv * 4 + 0) * 64 + lane];                                  \
    v8h a1 = Af[(wv * 4 + 1) * 64 + lane];                                  \
    v8h a2 = Af[(wv * 4 + 2) * 64 + lane];                                  \
    v8h a3 = Af[(wv * 4 + 3) * 64 + lane];                                  \
    const int grb = blockIdx.x * 64 + wv * 16 + q_ * 4;

#define MM_RELOAD_A(SRC)                                                    \
    a0 = SRC[(wv * 4 + 0) * 64 + lane];                                     \
    a1 = SRC[(wv * 4 + 1) * 64 + lane];                                     \
    a2 = SRC[(wv * 4 + 2) * 64 + lane];                                     \
    a3 = SRC[(wv * 4 + 3) * 64 + lane];

// B direct-from-global compute pass; epilogue (__VA_ARGS__) sees (c, col, grb, nt, M).
#define MM_COMPUTE_B(WPTR, ...)                                             \
    {                                                                       \
        const v8h* Bp_ = (const v8h*)(WPTR) + lane;                         \
        _Pragma("unroll") for (int nt = 0; nt < 8; ++nt) {                  \
            v8h b0 = Bp_[nt * 256];                                         \
            v8h b1v = Bp_[nt * 256 + 64];                                   \
            v8h b2v = Bp_[nt * 256 + 128];                                  \
            v8h b3v = Bp_[nt * 256 + 192];                                  \
            f32x4 c = {0.f, 0.f, 0.f, 0.f};                                 \
            c = MFMA16(a0, b0, c);                                          \
            c = MFMA16(a1, b1v, c);                                         \
            c = MFMA16(a2, b2v, c);                                         \
            c = MFMA16(a3, b3v, c);                                         \
            const int col = nt * 16 + c0_;                                  \
            __VA_ARGS__                                                     \
        }                                                                   \
    }

// C-frag (c[i] at row grb+i, col) -> f16 A-frag exchange write (wave-private region)
#define MM_EXCHANGE_IDX                                                     \
    int kt = col >> 5;                                                      \
    int o = col & 31;                                                       \
    int qp = o >> 3;                                                        \
    int j = o & 7;                                                          \
    int base = ((wv * 4 + kt) * 64 + qp * 16 + q_ * 4) * 8 + j;

// Xs AND Xrb from one A-stage (layer 0, A = h fp32 ld 224)
__launch_bounds__(256)
__global__ void k_mm_xsrb2(const float* __restrict__ A, int ldA,
                           const _Float16* __restrict__ Wp0, const float* __restrict__ b1,
                           _Float16* __restrict__ Xs, _Float16* __restrict__ Xrb, int M) {
    __shared__ v8h Af[1024];
    MM_STAGE_A_F32(A, ldA)
    MM_WAVE_PROLOG
    MM_COMPUTE_B(Wp0, {
        _Pragma("unroll") for (int i = 0; i < 4; ++i) {
            int gr = grb + i;
            if (gr < M) Xs[(size_t)gr * 128 + col] = (_Float16)c[i];
        }
    })
    MM_COMPUTE_B(Wp0 + 16384, {
        float bc = b1[col];
        _Pragma("unroll") for (int i = 0; i < 4; ++i) {
            int gr = grb + i;
            if (gr < M) Xrb[(size_t)gr * 128 + col] = (_Float16)(c[i] + bc);
        }
    })
}

// fused: S1 = Sin + P@w2 + deg*b2 (written once), then Xs/Xrb = S1 @ w1s/w1r (+b1)
__launch_bounds__(256)
__global__ void k_mm_accxsrb(const _Float16* __restrict__ P, const _Float16* __restrict__ Ww2,
                             const float* __restrict__ b2, const int* __restrict__ deg,
                             const float* __restrict__ Sin, int ldSin,
                             float* __restrict__ Sout,
                             const _Float16* __restrict__ Wp1, const float* __restrict__ b1,
                             _Float16* __restrict__ Xs, _Float16* __restrict__ Xrb, int M) {
    __shared__ v8h Af[1024];
    __shared__ v8h Af2[1024];
    MM_STAGE_A_F16(P)
    MM_WAVE_PROLOG
    _Float16* A2 = (_Float16*)Af2;
    MM_COMPUTE_B(Ww2, {
        float bc = b2[col];
        MM_EXCHANGE_IDX
        _Pragma("unroll") for (int i = 0; i < 4; ++i) {
            int gr = grb + i;
            float sv = 0.f;
            if (gr < M) {
                sv = Sin[(size_t)gr * ldSin + col] + c[i] + bc * (float)deg[gr];
                Sout[(size_t)gr * 128 + col] = sv;
            }
            A2[base + i * 8] = (_Float16)sv;
        }
    })
    __syncthreads();
    MM_RELOAD_A(Af2)
    MM_COMPUTE_B(Wp1, {
        _Pragma("unroll") for (int i = 0; i < 4; ++i) {
            int gr = grb + i;
            if (gr < M) Xs[(size_t)gr * 128 + col] = (_Float16)c[i];
        }
    })
    MM_COMPUTE_B(Wp1 + 16384, {
        float bc = b1[col];
        _Pragma("unroll") for (int i = 0; i < 4; ++i) {
            int gr = grb + i;
            if (gr < M) Xrb[(size_t)gr * 128 + col] = (_Float16)(c[i] + bc);
        }
    })
}

// fused: S2 = Sin + P@w2 + deg*b2 (register-resident); out = S2 + silu(S2@nw1+nb1)@nw2+nb2
__launch_bounds__(256)
__global__ void k_mm_accnode(const _Float16* __restrict__ P, const _Float16* __restrict__ Ww2,
                             const float* __restrict__ b2, const int* __restrict__ deg,
                             const float* __restrict__ Sin,
                             const _Float16* __restrict__ Wn1, const float* __restrict__ nb1,
                             const _Float16* __restrict__ Wn2, const float* __restrict__ nb2,
                             float* __restrict__ out, int M) {
    __shared__ v8h Af[1024];
    __shared__ v8h Af2[1024];
    MM_STAGE_A_F16(P)
    MM_WAVE_PROLOG
    float s2v[8][4];
    _Float16* A2 = (_Float16*)Af2;
    MM_COMPUTE_B(Ww2, {
        float bc = b2[col];
        MM_EXCHANGE_IDX
        _Pragma("unroll") for (int i = 0; i < 4; ++i) {
            int gr = grb + i;
            float sv = 0.f;
            if (gr < M) sv = Sin[(size_t)gr * 128 + col] + c[i] + bc * (float)deg[gr];
            s2v[nt][i] = sv;
            A2[base + i * 8] = (_Float16)sv;
        }
    })
    __syncthreads();
    MM_RELOAD_A(Af2)
    _Float16* A3 = (_Float16*)Af;        // Af free after prolog reads (wave-private writes)
    MM_COMPUTE_B(Wn1, {
        float bc = nb1[col];
        MM_EXCHANGE_IDX
        _Pragma("unroll") for (int i = 0; i < 4; ++i)
            A3[base + i * 8] = (_Float16)silu_f(c[i] + bc);
    })
    __syncthreads();
    MM_RELOAD_A(Af)
    MM_COMPUTE_B(Wn2, {
        float bc = nb2[col];
        _Pragma("unroll") for (int i = 0; i < 4; ++i) {
            int gr = grb + i;
            if (gr < M)
                out[(size_t)gr * NFEAT + col] = s2v[nt][i] + c[i] + bc;
        }
    })
}

// ---------------- edge aggregation: 2 receivers per wave; scalar payloads;
// gather software pipeline; masked final block (no scalar tail);
// Pade-tanh silu on packed _Float16 vectors (1 rcp).
__device__ __forceinline__ v2h silu2_pk(v2h pre) {
    // silu(x) ~= h*(1+u), h=x/2, u=tanh-Pade(clamp(h,+-3)) = z(27+z^2)/(27+9z^2)
    const v2h h27 = {(_Float16)27.f, (_Float16)27.f};
    const v2h hp3 = {(_Float16)3.f, (_Float16)3.f};
    const v2h hn3 = {(_Float16)-3.f, (_Float16)-3.f};
    v2h h = pre * (_Float16)0.5f;
    v2h z = __builtin_elementwise_min(__builtin_elementwise_max(h, hn3), hp3);
    v2h z2 = z * z;
    v2h num = z * (z2 + h27);
    v2h den = z2 * (_Float16)9.f + h27;
    __half2 rd = h2rcp(__builtin_bit_cast(__half2, den));
    v2h u = num * __builtin_bit_cast(v2h, rd);
    return h * u + h;
}

// load 8 payloads for block starting at k, index clamped to last (valid dupes)
__device__ __forceinline__ void load_blk_pay(const unsigned* __restrict__ ep, int k,
                                             int last, unsigned p[8]) {
#pragma unroll
    for (int u = 0; u < 8; ++u) { int i = k + u; p[u] = ep[i <= last ? i : last]; }
}

__device__ __forceinline__ void load_blk_x(const v2h* __restrict__ Xs, int lane,
                                           const unsigned p[8], v2h x[8]) {
#pragma unroll
    for (int u = 0; u < 8; ++u) x[u] = Xs[(size_t)(p[u] & 0xFFFFu) * 64 + lane];
}

__device__ __forceinline__ void blk_full(const unsigned p[8], const v2h x[8],
                                         v2h xr, v2h wl, float& ax, float& ay) {
    v2h t2 = {(_Float16)0.f, (_Float16)0.f};
#pragma unroll
    for (int u = 0; u < 8; ++u) {
        _Float16 lv = __builtin_bit_cast(_Float16, (unsigned short)(p[u] >> 16));
        v2h pre = x[u] + xr + lv * wl;
        t2 = t2 + silu2_pk(pre);
    }
    ax += (float)t2[0]; ay += (float)t2[1];
}

// final (possibly partial) block: zero the clamped-duplicate contributions via
// fp16 mask folded into the accumulate (uniform per-u condition -> s_cselect)
__device__ __forceinline__ void blk_mask(const unsigned p[8], const v2h x[8],
                                         v2h xr, v2h wl, int rem, float& ax, float& ay) {
    v2h t2 = {(_Float16)0.f, (_Float16)0.f};
#pragma unroll
    for (int u = 0; u < 8; ++u) {
        _Float16 lv = __builtin_bit_cast(_Float16, (unsigned short)(p[u] >> 16));
        v2h pre = x[u] + xr + lv * wl;
        v2h s = silu2_pk(pre);
        _Float16 mu = (u < rem) ? (_Float16)1.f : (_Float16)0.f;
        v2h mv = {mu, mu};
        t2 = t2 + s * mv;
    }
    ax += (float)t2[0]; ay += (float)t2[1];
}

// one CSR row; pc/xc hold block 0 (preloaded by caller). 1-block gather lookahead.
__device__ __forceinline__ v2h edge_row(const unsigned* __restrict__ ep, int dg,
                                        v2h xr, v2h wl, const v2h* __restrict__ Xs,
                                        int lane, unsigned pc[8], v2h xc[8]) {
    float ax = 0.f, ay = 0.f;
    int nb = (dg + 7) >> 3;
    int last = dg - 1;
    int k = 0;
    for (int b = 0; b + 1 < nb; ++b, k += 8) {
        unsigned pn[8];
        v2h xn[8];
        load_blk_pay(ep, k + 8, last, pn);        // uniform -> s_load
        load_blk_x(Xs, lane, pn, xn);             // prefetch gathers (SGPR base + lane)
        blk_full(pc, xc, xr, wl, ax, ay);
#pragma unroll
        for (int u = 0; u < 8; ++u) { pc[u] = pn[u]; xc[u] = xn[u]; }
    }
    blk_mask(pc, xc, xr, wl, dg - k, ax, ay);
    v2h o = {(_Float16)ax, (_Float16)ay};
    return o;
}

__launch_bounds__(256)
__global__ void k_edge(const v2h* __restrict__ Xs, const v2h* __restrict__ Xrb,
                       const float* __restrict__ w1L, const unsigned* __restrict__ epack,
                       const int* __restrict__ rowstart, const int* __restrict__ deg,
                       v2h* __restrict__ P, int N) {
    int wid = (blockIdx.x * blockDim.x + threadIdx.x) >> 6;
    int lane = threadIdx.x & 63;
    int r0 = wid * 2;
    if (r0 >= N) return;
    int r1 = r0 + 1;
    int dg0 = __builtin_amdgcn_readfirstlane(deg[r0]);
    int lo0 = __builtin_amdgcn_readfirstlane(rowstart[r0]);
    int dg1 = 0, lo1 = 0;
    if (r1 < N) {
        dg1 = __builtin_amdgcn_readfirstlane(deg[r1]);
        lo1 = __builtin_amdgcn_readfirstlane(rowstart[r1]);
    }
    float2 wlf = *(const float2*)(w1L + lane * 2);
    v2h wl = {(_Float16)wlf.x, (_Float16)wlf.y};
    const unsigned* ep0 = epack + lo0;
    const unsigned* ep1 = epack + lo1;
    // dual prologue: issue BOTH rows' first-block payloads+gathers before any
    // compute, so row1's prologue latency hides under row0's edge loop.
    unsigned pc0[8]; v2h xc0[8];
    unsigned pc1[8]; v2h xc1[8];
    if (dg0) { load_blk_pay(ep0, 0, dg0 - 1, pc0); load_blk_x(Xs, lane, pc0, xc0); }
    if (dg1) { load_blk_pay(ep1, 0, dg1 - 1, pc1); load_blk_x(Xs, lane, pc1, xc1); }
    v2h xr0 = Xrb[(size_t)r0 * 64 + lane];
    v2h zero = {(_Float16)0.f, (_Float16)0.f};
    v2h xr1 = (r1 < N) ? Xrb[(size_t)r1 * 64 + lane] : zero;
    v2h o0 = dg0 ? edge_row(ep0, dg0, xr0, wl, Xs, lane, pc0, xc0) : zero;
    v2h o1 = dg1 ? edge_row(ep1, dg1, xr1, wl, Xs, lane, pc1, xc1) : zero;
    P[(size_t)r0 * 64 + lane] = o0;
    if (r1 < N) P[(size_t)r1 * 64 + lane] = o1;
}

extern "C" void kernel_launch(void* const* d_in, const int* in_sizes, int n_in,
                              void* d_out, int out_size, void* d_ws, size_t ws_size,
                              hipStream_t stream) {
    const float* h      = (const float*)d_in[0];
    const int*   eidx   = (const int*)d_in[1];
    const float* elen   = (const float*)d_in[2];
    const float* mp_w1  = (const float*)d_in[3];
    const float* mp_b1  = (const float*)d_in[4];
    const float* mp_w2  = (const float*)d_in[5];
    const float* mp_b2  = (const float*)d_in[6];
    const float* nu_w1  = (const float*)d_in[7];
    const float* nu_b1  = (const float*)d_in[8];
    const float* nu_w2  = (const float*)d_in[9];
    const float* nu_b2  = (const float*)d_in[10];
    float* out = (float*)d_out;

    const int N = in_sizes[0] / NFEAT;   // 50000
    const int E = in_sizes[2];           // 1600000
    const int* sender   = eidx;
    const int* receiver = eidx + E;

    char* w = (char*)d_ws;
    auto alloc = [&](size_t bytes) -> char* {
        char* p = w;
        w += (bytes + 255) & ~(size_t)255;
        return p;
    };
    float*    S1    = (float*)alloc((size_t)N * 128 * 4);
    _Float16* Pf    = (_Float16*)alloc((size_t)N * 128 * 2);
    _Float16* Xs16  = (_Float16*)alloc((size_t)N * 128 * 2);
    _Float16* Xrb16 = (_Float16*)alloc((size_t)N * 128 * 2);
    _Float16* Wp    = (_Float16*)alloc((size_t)8 * 16384 * 2);
    int*      br    = (int*)alloc((size_t)NB * CAP * 4);
    unsigned* bsl   = (unsigned*)alloc((size_t)NB * CAP * 4);
    unsigned* epack = (unsigned*)alloc((size_t)NB * CAP * 4);
    int*      deg      = (int*)alloc((size_t)N * 4);
    int*      rowstart = (int*)alloc((size_t)N * 4);
    int*      cnt      = (int*)alloc((size_t)NB * 4);

    (void)hipMemsetAsync(cnt, 0, (size_t)NB * 4, stream);
    k_prep<<<8 + (N + 9) / 10, 256, 0, stream>>>(mp_w1, mp_w2, nu_w1, nu_w2, Wp,
                                                 (const float4*)h, (float4*)out, N);
    const int chunk = 4096;
    cs_bucket<<<(E + chunk - 1) / chunk, 256, 0, stream>>>(receiver, sender, elen, cnt,
                                                           br, bsl, E, chunk);
    cs_csr<<<NB, 256, 0, stream>>>(cnt, br, bsl, deg, rowstart, epack, N);

    const int gb = (N + 63) / 64;                    // 782
    const int eb = (((N + 1) / 2) * 64 + 255) / 256; // 2 rows/wave -> 6250

    // layer 0: Xs/Xrb from h
    k_mm_xsrb2<<<gb, 256, 0, stream>>>(h, NFEAT, Wp, mp_b1, Xs16, Xrb16, N);
    k_edge<<<eb, 256, 0, stream>>>((const v2h*)Xs16, (const v2h*)Xrb16,
                                   mp_w1 + 32768, epack, rowstart, deg, (v2h*)Pf, N);
    // fused: S1 = h + P@w2_l0 + deg*b2_l0 ; Xs/Xrb = S1 @ w1_l1 (+b1_l1)
    k_mm_accxsrb<<<gb, 256, 0, stream>>>(Pf, Wp + (size_t)2 * 16384, mp_b2, deg,
                                         h, NFEAT, S1,
                                         Wp + (size_t)3 * 16384, mp_b1 + 128,
                                         Xs16, Xrb16, N);
    k_edge<<<eb, 256, 0, stream>>>((const v2h*)Xs16, (const v2h*)Xrb16,
                                   mp_w1 + 32896 + 32768, epack, rowstart, deg,
                                   (v2h*)Pf, N);
    // fused: S2 = S1 + P@w2_l1 + deg*b2_l1 (regs) ; out = S2 + MLP(S2)
    k_mm_accnode<<<gb, 256, 0, stream>>>(Pf, Wp + (size_t)5 * 16384, mp_b2 + 128, deg,
                                         S1,
                                         Wp + (size_t)6 * 16384, nu_b1,
                                         Wp + (size_t)7 * 16384, nu_b2,
                                         out, N);
}

// Round 2
// 421.014 us; speedup vs baseline: 1.0363x; 1.0363x over previous
//
#include <hip/hip_runtime.h>
#include <hip/hip_fp16.h>

// FlashACE: 2-layer edge-MLP message passing + node update, N=50000, E=1.6M, HID=128.
//   Xs = S@w1[0:128], Xrb = S@w1[128:256] + b1          (MFMA f16 GEMMs, B direct-global)
//   P[r] = sum_e silu(Xs[s_e] + Xrb[r] + len_e*w1[256]) (edge pass over CSR, scalar path)
//   S += P@w2 + deg*b2 ; out = S + MLP(S)               (MFMA f16 GEMMs)
// Round 12 = Round 10 (1 row/wave, proven 72us/dispatch) with two isolated
// inner-loop fixes, keeping the wave mapping and occupancy regime intact:
//   * ping-pong double-buffered gather pipeline (x2 unrolled) -> no pc/xc
//     register copies (was 16 v_mov per 8 edges ~ 2 instr/edge)
//   * masked final block replaces the scalar tail (avg 3.5 serial
//     load->use chains per row); clamped dup gathers are L1 hits, dup
//     contributions zeroed via uniform fp16 mask folded into the accumulate.

#define NFEAT 224
#define RBITS 8                 // receivers per bucket = 256
#define NB 196                  // ceil(50000/256)
#define CAP 10240               // bucket region capacity (mean 8163, sigma ~90)

typedef _Float16 v8h __attribute__((ext_vector_type(8)));
typedef _Float16 v2h __attribute__((ext_vector_type(2)));
typedef float f32x4 __attribute__((ext_vector_type(4)));

#define MFMA16(a, b, c) __builtin_amdgcn_mfma_f32_16x16x32_f16(a, b, c, 0, 0, 0)

__device__ __forceinline__ float silu_f(float x) {
    float e = __expf(-x);
    return x * __builtin_amdgcn_rcpf(1.0f + e);
}

// ---------------- prep: blocks 0..7 pack weights; rest copy h rest-cols -> out
__global__ void k_prep(const float* __restrict__ mp_w1, const float* __restrict__ mp_w2,
                       const float* __restrict__ nu_w1, const float* __restrict__ nu_w2,
                       _Float16* __restrict__ Wp,
                       const float4* __restrict__ h4, float4* __restrict__ out4, int N) {
    if (blockIdx.x < 8) {
        const float* srcs[8] = {
            mp_w1, mp_w1 + 16384, mp_w2,
            mp_w1 + 32896, mp_w1 + 32896 + 16384, mp_w2 + 16384,
            nu_w1, nu_w2
        };
        const float* W = srcs[blockIdx.x];
        _Float16* dst = Wp + (size_t)blockIdx.x * 16384;
        for (int i = 0; i < 8; ++i) {
            int u = threadIdx.x + i * 256;
            int nt = u >> 8;
            int kt = (u >> 6) & 3;
            int lane = u & 63;
            int kb = kt * 32 + (lane >> 4) * 8;
            int n = nt * 16 + (lane & 15);
#pragma unroll
            for (int j = 0; j < 8; ++j)
                dst[(size_t)u * 8 + j] = (_Float16)W[(size_t)(kb + j) * 128 + n];
        }
    } else {
        int b = blockIdx.x - 8;
        int t = threadIdx.x;
        if (t < 240) {
            int r = b * 10 + t / 24;
            int c = t % 24;
            if (r < N) out4[(size_t)r * 56 + 32 + c] = h4[(size_t)r * 56 + 32 + c];
        }
    }
}

// ---------------- counting sort pass 1: scatter edges into over-allocated buckets
__global__ void cs_bucket(const int* __restrict__ recv, const int* __restrict__ sender,
                          const float* __restrict__ elen, int* __restrict__ cnt,
                          int* __restrict__ br, unsigned* __restrict__ bsl,
                          int E, int chunk) {
    __shared__ int lhist[256];
    __shared__ int lcur[256];
    int t = threadIdx.x;
    int start = blockIdx.x * chunk;
    int end = start + chunk; if (end > E) end = E;
    lhist[t] = 0;
    __syncthreads();
    for (int i = start + t; i < end; i += 256)
        atomicAdd(&lhist[recv[i] >> RBITS], 1);
    __syncthreads();
    if (t < NB) {
        int c = lhist[t];
        lcur[t] = t * CAP + (c ? atomicAdd(&cnt[t], c) : 0);
    }
    __syncthreads();
    for (int i = start + t; i < end; i += 256) {
        int r = recv[i];
        int pos = atomicAdd(&lcur[r >> RBITS], 1);
        br[pos] = r;
        bsl[pos] = (unsigned)sender[i] |
                   ((unsigned)__half_as_ushort(__float2half_rn(elen[i])) << 16);
    }
}

// ---------------- counting sort pass 2: one wg per bucket -> CSR + deg/rowstart
__global__ void cs_csr(const int* __restrict__ cnt, const int* __restrict__ br,
                       const unsigned* __restrict__ bsl,
                       int* __restrict__ deg, int* __restrict__ rowstart,
                       unsigned* __restrict__ epack, int N) {
    __shared__ int hist[256];
    __shared__ int sh[256];
    __shared__ int lcur[256];
    int t = threadIdx.x;
    int b = blockIdx.x;
    int r0 = b << RBITS;
    int e0 = b * CAP;
    int e1 = e0 + cnt[b];
    hist[t] = 0;
    __syncthreads();
    for (int i = e0 + t; i < e1; i += 256)
        atomicAdd(&hist[br[i] & 255], 1);
    __syncthreads();
    sh[t] = hist[t];
    __syncthreads();
    for (int off = 1; off < 256; off <<= 1) {
        int add = (t >= off) ? sh[t - off] : 0;
        __syncthreads();
        sh[t] += add;
        __syncthreads();
    }
    int excl = (t == 0) ? 0 : sh[t - 1];
    lcur[t] = e0 + excl;
    int r = r0 + t;
    if (r < N) { deg[r] = hist[t]; rowstart[r] = e0 + excl; }
    __syncthreads();
    for (int i = e0 + t; i < e1; i += 256) {
        int rr = br[i];
        int pos = atomicAdd(&lcur[rr & 255], 1);
        epack[pos] = bsl[i];
    }
}

// ================ MFMA GEMM core: M-tile 64, N=K=128, 256 thr (4 waves) ================
// A staged via LDS. B fragments load DIRECTLY from global (coalesced, L2-hot).

#define MM_STAGE_A_F32(Aptr, ldA)                                           \
    _Pragma("unroll") for (int i = 0; i < 4; ++i) {                         \
        int u = threadIdx.x + i * 256;                                      \
        int r = u >> 4;                                                     \
        int g = u & 15;                                                     \
        int gr = blockIdx.x * 64 + r;                                       \
        float4 x0 = make_float4(0.f, 0.f, 0.f, 0.f);                        \
        float4 x1 = x0;                                                     \
        if (gr < M) {                                                       \
            const float* s_ = (Aptr) + (size_t)gr * (ldA) + g * 8;          \
            x0 = *(const float4*)s_;                                        \
            x1 = *(const float4*)(s_ + 4);                                  \
        }                                                                   \
        v8h hv;                                                             \
        hv[0] = (_Float16)x0.x; hv[1] = (_Float16)x0.y;                     \
        hv[2] = (_Float16)x0.z; hv[3] = (_Float16)x0.w;                     \
        hv[4] = (_Float16)x1.x; hv[5] = (_Float16)x1.y;                     \
        hv[6] = (_Float16)x1.z; hv[7] = (_Float16)x1.w;                     \
        Af[((r >> 4) * 4 + (g >> 2)) * 64 + (g & 3) * 16 + (r & 15)] = hv;  \
    }

#define MM_STAGE_A_F16(Aptr)                                                \
    _Pragma("unroll") for (int i = 0; i < 4; ++i) {                         \
        int u = threadIdx.x + i * 256;                                      \
        int r = u >> 4;                                                     \
        int g = u & 15;                                                     \
        int gr = blockIdx.x * 64 + r;                                       \
        float4 x = make_float4(0.f, 0.f, 0.f, 0.f);                         \
        if (gr < M) x = *(const float4*)((Aptr) + (size_t)gr * 128 + g * 8);\
        *(float4*)&Af[((r >> 4) * 4 + (g >> 2)) * 64 + (g & 3) * 16 + (r & 15)] = x; \
    }

#define MM_WAVE_PROLOG                                                      \
    __syncthreads();                                                        \
    const int wv = threadIdx.x >> 6;                                        \
    const int lane = threadIdx.x & 63;                                      \
    const int q_ = lane >> 4;                                               \
    const int c0_ = lane & 15;                                              \
    v8h a0 = Af[(wv * 4 + 0) * 64 + lane];                                  \
    v8h a1 = Af[(wv * 4 + 1) * 64 + lane];                                  \
    v8h a2 = Af[(wv * 4 + 2) * 64 + lane];                                  \
    v8h a3 = Af[(wv * 4 + 3) * 64 + lane];                                  \
    const int grb = blockIdx.x * 64 + wv * 16 + q_ * 4;

#define MM_RELOAD_A(SRC)                                                    \
    a0 = SRC[(wv * 4 + 0) * 64 + lane];                                     \
    a1 = SRC[(wv * 4 + 1) * 64 + lane];                                     \
    a2 = SRC[(wv * 4 + 2) * 64 + lane];                                     \
    a3 = SRC[(wv * 4 + 3) * 64 + lane];

// B direct-from-global compute pass; epilogue (__VA_ARGS__) sees (c, col, grb, nt, M).
#define MM_COMPUTE_B(WPTR, ...)                                             \
    {                                                                       \
        const v8h* Bp_ = (const v8h*)(WPTR) + lane;                         \
        _Pragma("unroll") for (int nt = 0; nt < 8; ++nt) {                  \
            v8h b0 = Bp_[nt * 256];                                         \
            v8h b1v = Bp_[nt * 256 + 64];                                   \
            v8h b2v = Bp_[nt * 256 + 128];                                  \
            v8h b3v = Bp_[nt * 256 + 192];                                  \
            f32x4 c = {0.f, 0.f, 0.f, 0.f};                                 \
            c = MFMA16(a0, b0, c);                                          \
            c = MFMA16(a1, b1v, c);                                         \
            c = MFMA16(a2, b2v, c);                                         \
            c = MFMA16(a3, b3v, c);                                         \
            const int col = nt * 16 + c0_;                                  \
            __VA_ARGS__                                                     \
        }                                                                   \
    }

// C-frag (c[i] at row grb+i, col) -> f16 A-frag exchange write (wave-private region)
#define MM_EXCHANGE_IDX                                                     \
    int kt = col >> 5;                                                      \
    int o = col & 31;                                                       \
    int qp = o >> 3;                                                        \
    int j = o & 7;                                                          \
    int base = ((wv * 4 + kt) * 64 + qp * 16 + q_ * 4) * 8 + j;

// Xs AND Xrb from one A-stage (layer 0, A = h fp32 ld 224)
__launch_bounds__(256)
__global__ void k_mm_xsrb2(const float* __restrict__ A, int ldA,
                           const _Float16* __restrict__ Wp0, const float* __restrict__ b1,
                           _Float16* __restrict__ Xs, _Float16* __restrict__ Xrb, int M) {
    __shared__ v8h Af[1024];
    MM_STAGE_A_F32(A, ldA)
    MM_WAVE_PROLOG
    MM_COMPUTE_B(Wp0, {
        _Pragma("unroll") for (int i = 0; i < 4; ++i) {
            int gr = grb + i;
            if (gr < M) Xs[(size_t)gr * 128 + col] = (_Float16)c[i];
        }
    })
    MM_COMPUTE_B(Wp0 + 16384, {
        float bc = b1[col];
        _Pragma("unroll") for (int i = 0; i < 4; ++i) {
            int gr = grb + i;
            if (gr < M) Xrb[(size_t)gr * 128 + col] = (_Float16)(c[i] + bc);
        }
    })
}

// fused: S1 = Sin + P@w2 + deg*b2 (written once), then Xs/Xrb = S1 @ w1s/w1r (+b1)
__launch_bounds__(256)
__global__ void k_mm_accxsrb(const _Float16* __restrict__ P, const _Float16* __restrict__ Ww2,
                             const float* __restrict__ b2, const int* __restrict__ deg,
                             const float* __restrict__ Sin, int ldSin,
                             float* __restrict__ Sout,
                             const _Float16* __restrict__ Wp1, const float* __restrict__ b1,
                             _Float16* __restrict__ Xs, _Float16* __restrict__ Xrb, int M) {
    __shared__ v8h Af[1024];
    __shared__ v8h Af2[1024];
    MM_STAGE_A_F16(P)
    MM_WAVE_PROLOG
    _Float16* A2 = (_Float16*)Af2;
    MM_COMPUTE_B(Ww2, {
        float bc = b2[col];
        MM_EXCHANGE_IDX
        _Pragma("unroll") for (int i = 0; i < 4; ++i) {
            int gr = grb + i;
            float sv = 0.f;
            if (gr < M) {
                sv = Sin[(size_t)gr * ldSin + col] + c[i] + bc * (float)deg[gr];
                Sout[(size_t)gr * 128 + col] = sv;
            }
            A2[base + i * 8] = (_Float16)sv;
        }
    })
    __syncthreads();
    MM_RELOAD_A(Af2)
    MM_COMPUTE_B(Wp1, {
        _Pragma("unroll") for (int i = 0; i < 4; ++i) {
            int gr = grb + i;
            if (gr < M) Xs[(size_t)gr * 128 + col] = (_Float16)c[i];
        }
    })
    MM_COMPUTE_B(Wp1 + 16384, {
        float bc = b1[col];
        _Pragma("unroll") for (int i = 0; i < 4; ++i) {
            int gr = grb + i;
            if (gr < M) Xrb[(size_t)gr * 128 + col] = (_Float16)(c[i] + bc);
        }
    })
}

// fused: S2 = Sin + P@w2 + deg*b2 (register-resident); out = S2 + silu(S2@nw1+nb1)@nw2+nb2
__launch_bounds__(256)
__global__ void k_mm_accnode(const _Float16* __restrict__ P, const _Float16* __restrict__ Ww2,
                             const float* __restrict__ b2, const int* __restrict__ deg,
                             const float* __restrict__ Sin,
                             const _Float16* __restrict__ Wn1, const float* __restrict__ nb1,
                             const _Float16* __restrict__ Wn2, const float* __restrict__ nb2,
                             float* __restrict__ out, int M) {
    __shared__ v8h Af[1024];
    __shared__ v8h Af2[1024];
    MM_STAGE_A_F16(P)
    MM_WAVE_PROLOG
    float s2v[8][4];
    _Float16* A2 = (_Float16*)Af2;
    MM_COMPUTE_B(Ww2, {
        float bc = b2[col];
        MM_EXCHANGE_IDX
        _Pragma("unroll") for (int i = 0; i < 4; ++i) {
            int gr = grb + i;
            float sv = 0.f;
            if (gr < M) sv = Sin[(size_t)gr * 128 + col] + c[i] + bc * (float)deg[gr];
            s2v[nt][i] = sv;
            A2[base + i * 8] = (_Float16)sv;
        }
    })
    __syncthreads();
    MM_RELOAD_A(Af2)
    _Float16* A3 = (_Float16*)Af;        // Af free after prolog reads (wave-private writes)
    MM_COMPUTE_B(Wn1, {
        float bc = nb1[col];
        MM_EXCHANGE_IDX
        _Pragma("unroll") for (int i = 0; i < 4; ++i)
            A3[base + i * 8] = (_Float16)silu_f(c[i] + bc);
    })
    __syncthreads();
    MM_RELOAD_A(Af)
    MM_COMPUTE_B(Wn2, {
        float bc = nb2[col];
        _Pragma("unroll") for (int i = 0; i < 4; ++i) {
            int gr = grb + i;
            if (gr < M)
                out[(size_t)gr * NFEAT + col] = s2v[nt][i] + c[i] + bc;
        }
    })
}

// ---------------- edge aggregation: one wave per receiver; scalar payloads;
// ping-pong double-buffered gather pipeline (no register copies); masked final
// block (no scalar tail); Pade-tanh silu on packed _Float16 vectors (1 rcp).
__device__ __forceinline__ v2h silu2_pk(v2h pre) {
    // silu(x) ~= h*(1+u), h=x/2, u=tanh-Pade(clamp(h,+-3)) = z(27+z^2)/(27+9z^2)
    const v2h h27 = {(_Float16)27.f, (_Float16)27.f};
    const v2h hp3 = {(_Float16)3.f, (_Float16)3.f};
    const v2h hn3 = {(_Float16)-3.f, (_Float16)-3.f};
    v2h h = pre * (_Float16)0.5f;
    v2h z = __builtin_elementwise_min(__builtin_elementwise_max(h, hn3), hp3);
    v2h z2 = z * z;
    v2h num = z * (z2 + h27);
    v2h den = z2 * (_Float16)9.f + h27;
    __half2 rd = h2rcp(__builtin_bit_cast(__half2, den));
    v2h u = num * __builtin_bit_cast(v2h, rd);
    return h * u + h;
}

// load 8 payloads for block starting at k, index clamped to last (valid dupes)
__device__ __forceinline__ void load_blk_pay(const unsigned* __restrict__ ep, int k,
                                             int last, unsigned p[8]) {
#pragma unroll
    for (int u = 0; u < 8; ++u) { int i = k + u; p[u] = ep[i <= last ? i : last]; }
}

__device__ __forceinline__ void load_blk_x(const v2h* __restrict__ Xs, int lane,
                                           const unsigned p[8], v2h x[8]) {
#pragma unroll
    for (int u = 0; u < 8; ++u) x[u] = Xs[(size_t)(p[u] & 0xFFFFu) * 64 + lane];
}

__device__ __forceinline__ void blk_full(const unsigned p[8], const v2h x[8],
                                         v2h xr, v2h wl, float& ax, float& ay) {
    v2h t2 = {(_Float16)0.f, (_Float16)0.f};
#pragma unroll
    for (int u = 0; u < 8; ++u) {
        _Float16 lv = __builtin_bit_cast(_Float16, (unsigned short)(p[u] >> 16));
        v2h pre = x[u] + xr + lv * wl;
        t2 = t2 + silu2_pk(pre);
    }
    ax += (float)t2[0]; ay += (float)t2[1];
}

// final (possibly partial) block: zero the clamped-duplicate contributions via
// fp16 mask folded into the accumulate (uniform per-u condition -> s_cselect)
__device__ __forceinline__ void blk_mask(const unsigned p[8], const v2h x[8],
                                         v2h xr, v2h wl, int rem, float& ax, float& ay) {
    v2h t2 = {(_Float16)0.f, (_Float16)0.f};
#pragma unroll
    for (int u = 0; u < 8; ++u) {
        _Float16 lv = __builtin_bit_cast(_Float16, (unsigned short)(p[u] >> 16));
        v2h pre = x[u] + xr + lv * wl;
        v2h s = silu2_pk(pre);
        _Float16 mu = (u < rem) ? (_Float16)1.f : (_Float16)0.f;
        v2h mv = {mu, mu};
        t2 = t2 + s * mv;
    }
    ax += (float)t2[0]; ay += (float)t2[1];
}

// one CSR row; pA/xA hold block 0 (preloaded by caller, clamped).
// Ping-pong: process blocks in pairs, always issuing the next block's loads
// before computing the current one. Final block is masked, never a scalar tail.
__device__ __forceinline__ v2h edge_row(const unsigned* __restrict__ ep, int dg,
                                        v2h xr, v2h wl, const v2h* __restrict__ Xs,
                                        int lane, unsigned pA[8], v2h xA[8]) {
    float ax = 0.f, ay = 0.f;
    int nb = (dg + 7) >> 3;
    int last = dg - 1;
    int rem = dg - ((nb - 1) << 3);   // 1..8 valid edges in final block
    unsigned pB[8]; v2h xB[8];
    int b = 0;
    while (b + 2 <= nb - 1) {
        load_blk_pay(ep, (b + 1) << 3, last, pB);   // uniform -> s_load
        load_blk_x(Xs, lane, pB, xB);               // prefetch gathers
        blk_full(pA, xA, xr, wl, ax, ay);
        load_blk_pay(ep, (b + 2) << 3, last, pA);
        load_blk_x(Xs, lane, pA, xA);
        blk_full(pB, xB, xr, wl, ax, ay);
        b += 2;
    }
    if (b == nb - 1) {
        blk_mask(pA, xA, xr, wl, rem, ax, ay);
    } else {              // b == nb-2: one more full block, then masked final
        load_blk_pay(ep, (b + 1) << 3, last, pB);
        load_blk_x(Xs, lane, pB, xB);
        blk_full(pA, xA, xr, wl, ax, ay);
        blk_mask(pB, xB, xr, wl, rem, ax, ay);
    }
    v2h o = {(_Float16)ax, (_Float16)ay};
    return o;
}

__launch_bounds__(256)
__global__ void k_edge(const v2h* __restrict__ Xs, const v2h* __restrict__ Xrb,
                       const float* __restrict__ w1L, const unsigned* __restrict__ epack,
                       const int* __restrict__ rowstart, const int* __restrict__ deg,
                       v2h* __restrict__ P, int N) {
    int wid = (blockIdx.x * blockDim.x + threadIdx.x) >> 6;
    int lane = threadIdx.x & 63;
    if (wid >= N) return;
    int dg = __builtin_amdgcn_readfirstlane(deg[wid]);
    int lo = __builtin_amdgcn_readfirstlane(rowstart[wid]);
    const unsigned* ep = epack + lo;
    float2 wlf = *(const float2*)(w1L + lane * 2);
    v2h wl = {(_Float16)wlf.x, (_Float16)wlf.y};
    unsigned pA[8]; v2h xA[8];
    if (dg) { load_blk_pay(ep, 0, dg - 1, pA); load_blk_x(Xs, lane, pA, xA); }
    v2h xr = Xrb[(size_t)wid * 64 + lane];
    v2h zero = {(_Float16)0.f, (_Float16)0.f};
    v2h o = dg ? edge_row(ep, dg, xr, wl, Xs, lane, pA, xA) : zero;
    P[(size_t)wid * 64 + lane] = o;
}

extern "C" void kernel_launch(void* const* d_in, const int* in_sizes, int n_in,
                              void* d_out, int out_size, void* d_ws, size_t ws_size,
                              hipStream_t stream) {
    const float* h      = (const float*)d_in[0];
    const int*   eidx   = (const int*)d_in[1];
    const float* elen   = (const float*)d_in[2];
    const float* mp_w1  = (const float*)d_in[3];
    const float* mp_b1  = (const float*)d_in[4];
    const float* mp_w2  = (const float*)d_in[5];
    const float* mp_b2  = (const float*)d_in[6];
    const float* nu_w1  = (const float*)d_in[7];
    const float* nu_b1  = (const float*)d_in[8];
    const float* nu_w2  = (const float*)d_in[9];
    const float* nu_b2  = (const float*)d_in[10];
    float* out = (float*)d_out;

    const int N = in_sizes[0] / NFEAT;   // 50000
    const int E = in_sizes[2];           // 1600000
    const int* sender   = eidx;
    const int* receiver = eidx + E;

    char* w = (char*)d_ws;
    auto alloc = [&](size_t bytes) -> char* {
        char* p = w;
        w += (bytes + 255) & ~(size_t)255;
        return p;
    };
    float*    S1    = (float*)alloc((size_t)N * 128 * 4);
    _Float16* Pf    = (_Float16*)alloc((size_t)N * 128 * 2);
    _Float16* Xs16  = (_Float16*)alloc((size_t)N * 128 * 2);
    _Float16* Xrb16 = (_Float16*)alloc((size_t)N * 128 * 2);
    _Float16* Wp    = (_Float16*)alloc((size_t)8 * 16384 * 2);
    int*      br    = (int*)alloc((size_t)NB * CAP * 4);
    unsigned* bsl   = (unsigned*)alloc((size_t)NB * CAP * 4);
    unsigned* epack = (unsigned*)alloc((size_t)NB * CAP * 4);
    int*      deg      = (int*)alloc((size_t)N * 4);
    int*      rowstart = (int*)alloc((size_t)N * 4);
    int*      cnt      = (int*)alloc((size_t)NB * 4);

    (void)hipMemsetAsync(cnt, 0, (size_t)NB * 4, stream);
    k_prep<<<8 + (N + 9) / 10, 256, 0, stream>>>(mp_w1, mp_w2, nu_w1, nu_w2, Wp,
                                                 (const float4*)h, (float4*)out, N);
    const int chunk = 4096;
    cs_bucket<<<(E + chunk - 1) / chunk, 256, 0, stream>>>(receiver, sender, elen, cnt,
                                                           br, bsl, E, chunk);
    cs_csr<<<NB, 256, 0, stream>>>(cnt, br, bsl, deg, rowstart, epack, N);

    const int gb = (N + 63) / 64;            // 782
    const int eb = (N * 64 + 255) / 256;     // 1 row/wave -> 12500

    // layer 0: Xs/Xrb from h
    k_mm_xsrb2<<<gb, 256, 0, stream>>>(h, NFEAT, Wp, mp_b1, Xs16, Xrb16, N);
    k_edge<<<eb, 256, 0, stream>>>((const v2h*)Xs16, (const v2h*)Xrb16,
                                   mp_w1 + 32768, epack, rowstart, deg, (v2h*)Pf, N);
    // fused: S1 = h + P@w2_l0 + deg*b2_l0 ; Xs/Xrb = S1 @ w1_l1 (+b1_l1)
    k_mm_accxsrb<<<gb, 256, 0, stream>>>(Pf, Wp + (size_t)2 * 16384, mp_b2, deg,
                                         h, NFEAT, S1,
                                         Wp + (size_t)3 * 16384, mp_b1 + 128,
                                         Xs16, Xrb16, N);
    k_edge<<<eb, 256, 0, stream>>>((const v2h*)Xs16, (const v2h*)Xrb16,
                                   mp_w1 + 32896 + 32768, epack, rowstart, deg,
                                   (v2h*)Pf, N);
    // fused: S2 = S1 + P@w2_l1 + deg*b2_l1 (regs) ; out = S2 + MLP(S2)
    k_mm_accnode<<<gb, 256, 0, stream>>>(Pf, Wp + (size_t)5 * 16384, mp_b2 + 128, deg,
                                         S1,
                                         Wp + (size_t)6 * 16384, nu_b1,
                                         Wp + (size_t)7 * 16384, nu_b2,
                                         out, N);
}

// Round 3
// 378.896 us; speedup vs baseline: 1.1514x; 1.1112x over previous
//
#include <hip/hip_runtime.h>
#include <hip/hip_fp16.h>

// FlashACE: 2-layer edge-MLP message passing + node update, N=50000, E=1.6M, HID=128.
//   Xs = S@w1[0:128], Xrb = S@w1[128:256] + b1          (MFMA f16 GEMMs, B direct-global)
//   P[r] = sum_e silu(Xs[s_e] + Xrb[r] + len_e*w1[256]) (edge pass over CSR, scalar path)
//   S += P@w2 + deg*b2 ; out = S + MLP(S)               (MFMA f16 GEMMs)
// Round 13 = Round 10 structure verbatim (1 row/wave, copy-pipeline, scalar
// tail -- the proven 72us/dispatch regime; rounds 11/12 restructures both
// regressed) with ONE change: silu via odd deg-9 polynomial tanh (pure
// v_pk_fma Horner, ZERO transcendentals). h2rcp lowered to 2x quarter-rate
// v_rcp_f16 (~16 cy/edge, ~40% of k_edge VALU time). Poly max u-error 0.009,
// strictly better than the previously-passing Pade (0.019 at z=2.1).

#define NFEAT 224
#define RBITS 8                 // receivers per bucket = 256
#define NB 196                  // ceil(50000/256)
#define CAP 10240               // bucket region capacity (mean 8163, sigma ~90)

typedef _Float16 v8h __attribute__((ext_vector_type(8)));
typedef _Float16 v2h __attribute__((ext_vector_type(2)));
typedef float f32x4 __attribute__((ext_vector_type(4)));

#define MFMA16(a, b, c) __builtin_amdgcn_mfma_f32_16x16x32_f16(a, b, c, 0, 0, 0)

__device__ __forceinline__ float silu_f(float x) {
    float e = __expf(-x);
    return x * __builtin_amdgcn_rcpf(1.0f + e);
}

// ---------------- prep: blocks 0..7 pack weights; rest copy h rest-cols -> out
__global__ void k_prep(const float* __restrict__ mp_w1, const float* __restrict__ mp_w2,
                       const float* __restrict__ nu_w1, const float* __restrict__ nu_w2,
                       _Float16* __restrict__ Wp,
                       const float4* __restrict__ h4, float4* __restrict__ out4, int N) {
    if (blockIdx.x < 8) {
        const float* srcs[8] = {
            mp_w1, mp_w1 + 16384, mp_w2,
            mp_w1 + 32896, mp_w1 + 32896 + 16384, mp_w2 + 16384,
            nu_w1, nu_w2
        };
        const float* W = srcs[blockIdx.x];
        _Float16* dst = Wp + (size_t)blockIdx.x * 16384;
        for (int i = 0; i < 8; ++i) {
            int u = threadIdx.x + i * 256;
            int nt = u >> 8;
            int kt = (u >> 6) & 3;
            int lane = u & 63;
            int kb = kt * 32 + (lane >> 4) * 8;
            int n = nt * 16 + (lane & 15);
#pragma unroll
            for (int j = 0; j < 8; ++j)
                dst[(size_t)u * 8 + j] = (_Float16)W[(size_t)(kb + j) * 128 + n];
        }
    } else {
        int b = blockIdx.x - 8;
        int t = threadIdx.x;
        if (t < 240) {
            int r = b * 10 + t / 24;
            int c = t % 24;
            if (r < N) out4[(size_t)r * 56 + 32 + c] = h4[(size_t)r * 56 + 32 + c];
        }
    }
}

// ---------------- counting sort pass 1: scatter edges into over-allocated buckets
__global__ void cs_bucket(const int* __restrict__ recv, const int* __restrict__ sender,
                          const float* __restrict__ elen, int* __restrict__ cnt,
                          int* __restrict__ br, unsigned* __restrict__ bsl,
                          int E, int chunk) {
    __shared__ int lhist[256];
    __shared__ int lcur[256];
    int t = threadIdx.x;
    int start = blockIdx.x * chunk;
    int end = start + chunk; if (end > E) end = E;
    lhist[t] = 0;
    __syncthreads();
    for (int i = start + t; i < end; i += 256)
        atomicAdd(&lhist[recv[i] >> RBITS], 1);
    __syncthreads();
    if (t < NB) {
        int c = lhist[t];
        lcur[t] = t * CAP + (c ? atomicAdd(&cnt[t], c) : 0);
    }
    __syncthreads();
    for (int i = start + t; i < end; i += 256) {
        int r = recv[i];
        int pos = atomicAdd(&lcur[r >> RBITS], 1);
        br[pos] = r;
        bsl[pos] = (unsigned)sender[i] |
                   ((unsigned)__half_as_ushort(__float2half_rn(elen[i])) << 16);
    }
}

// ---------------- counting sort pass 2: one wg per bucket -> CSR + deg/rowstart
__global__ void cs_csr(const int* __restrict__ cnt, const int* __restrict__ br,
                       const unsigned* __restrict__ bsl,
                       int* __restrict__ deg, int* __restrict__ rowstart,
                       unsigned* __restrict__ epack, int N) {
    __shared__ int hist[256];
    __shared__ int sh[256];
    __shared__ int lcur[256];
    int t = threadIdx.x;
    int b = blockIdx.x;
    int r0 = b << RBITS;
    int e0 = b * CAP;
    int e1 = e0 + cnt[b];
    hist[t] = 0;
    __syncthreads();
    for (int i = e0 + t; i < e1; i += 256)
        atomicAdd(&hist[br[i] & 255], 1);
    __syncthreads();
    sh[t] = hist[t];
    __syncthreads();
    for (int off = 1; off < 256; off <<= 1) {
        int add = (t >= off) ? sh[t - off] : 0;
        __syncthreads();
        sh[t] += add;
        __syncthreads();
    }
    int excl = (t == 0) ? 0 : sh[t - 1];
    lcur[t] = e0 + excl;
    int r = r0 + t;
    if (r < N) { deg[r] = hist[t]; rowstart[r] = e0 + excl; }
    __syncthreads();
    for (int i = e0 + t; i < e1; i += 256) {
        int rr = br[i];
        int pos = atomicAdd(&lcur[rr & 255], 1);
        epack[pos] = bsl[i];
    }
}

// ================ MFMA GEMM core: M-tile 64, N=K=128, 256 thr (4 waves) ================
// A staged via LDS. B fragments load DIRECTLY from global (coalesced, L2-hot).

#define MM_STAGE_A_F32(Aptr, ldA)                                           \
    _Pragma("unroll") for (int i = 0; i < 4; ++i) {                         \
        int u = threadIdx.x + i * 256;                                      \
        int r = u >> 4;                                                     \
        int g = u & 15;                                                     \
        int gr = blockIdx.x * 64 + r;                                       \
        float4 x0 = make_float4(0.f, 0.f, 0.f, 0.f);                        \
        float4 x1 = x0;                                                     \
        if (gr < M) {                                                       \
            const float* s_ = (Aptr) + (size_t)gr * (ldA) + g * 8;          \
            x0 = *(const float4*)s_;                                        \
            x1 = *(const float4*)(s_ + 4);                                  \
        }                                                                   \
        v8h hv;                                                             \
        hv[0] = (_Float16)x0.x; hv[1] = (_Float16)x0.y;                     \
        hv[2] = (_Float16)x0.z; hv[3] = (_Float16)x0.w;                     \
        hv[4] = (_Float16)x1.x; hv[5] = (_Float16)x1.y;                     \
        hv[6] = (_Float16)x1.z; hv[7] = (_Float16)x1.w;                     \
        Af[((r >> 4) * 4 + (g >> 2)) * 64 + (g & 3) * 16 + (r & 15)] = hv;  \
    }

#define MM_STAGE_A_F16(Aptr)                                                \
    _Pragma("unroll") for (int i = 0; i < 4; ++i) {                         \
        int u = threadIdx.x + i * 256;                                      \
        int r = u >> 4;                                                     \
        int g = u & 15;                                                     \
        int gr = blockIdx.x * 64 + r;                                       \
        float4 x = make_float4(0.f, 0.f, 0.f, 0.f);                         \
        if (gr < M) x = *(const float4*)((Aptr) + (size_t)gr * 128 + g * 8);\
        *(float4*)&Af[((r >> 4) * 4 + (g >> 2)) * 64 + (g & 3) * 16 + (r & 15)] = x; \
    }

#define MM_WAVE_PROLOG                                                      \
    __syncthreads();                                                        \
    const int wv = threadIdx.x >> 6;                                        \
    const int lane = threadIdx.x & 63;                                      \
    const int q_ = lane >> 4;                                               \
    const int c0_ = lane & 15;                                              \
    v8h a0 = Af[(wv * 4 + 0) * 64 + lane];                                  \
    v8h a1 = Af[(wv * 4 + 1) * 64 + lane];                                  \
    v8h a2 = Af[(wv * 4 + 2) * 64 + lane];                                  \
    v8h a3 = Af[(wv * 4 + 3) * 64 + lane];                                  \
    const int grb = blockIdx.x * 64 + wv * 16 + q_ * 4;

#define MM_RELOAD_A(SRC)                                                    \
    a0 = SRC[(wv * 4 + 0) * 64 + lane];                                     \
    a1 = SRC[(wv * 4 + 1) * 64 + lane];                                     \
    a2 = SRC[(wv * 4 + 2) * 64 + lane];                                     \
    a3 = SRC[(wv * 4 + 3) * 64 + lane];

// B direct-from-global compute pass; epilogue (__VA_ARGS__) sees (c, col, grb, nt, M).
#define MM_COMPUTE_B(WPTR, ...)                                             \
    {                                                                       \
        const v8h* Bp_ = (const v8h*)(WPTR) + lane;                         \
        _Pragma("unroll") for (int nt = 0; nt < 8; ++nt) {                  \
            v8h b0 = Bp_[nt * 256];                                         \
            v8h b1v = Bp_[nt * 256 + 64];                                   \
            v8h b2v = Bp_[nt * 256 + 128];                                  \
            v8h b3v = Bp_[nt * 256 + 192];                                  \
            f32x4 c = {0.f, 0.f, 0.f, 0.f};                                 \
            c = MFMA16(a0, b0, c);                                          \
            c = MFMA16(a1, b1v, c);                                         \
            c = MFMA16(a2, b2v, c);                                         \
            c = MFMA16(a3, b3v, c);                                         \
            const int col = nt * 16 + c0_;                                  \
            __VA_ARGS__                                                     \
        }                                                                   \
    }

// C-frag (c[i] at row grb+i, col) -> f16 A-frag exchange write (wave-private region)
#define MM_EXCHANGE_IDX                                                     \
    int kt = col >> 5;                                                      \
    int o = col & 31;                                                       \
    int qp = o >> 3;                                                        \
    int j = o & 7;                                                          \
    int base = ((wv * 4 + kt) * 64 + qp * 16 + q_ * 4) * 8 + j;

// Xs AND Xrb from one A-stage (layer 0, A = h fp32 ld 224)
__launch_bounds__(256)
__global__ void k_mm_xsrb2(const float* __restrict__ A, int ldA,
                           const _Float16* __restrict__ Wp0, const float* __restrict__ b1,
                           _Float16* __restrict__ Xs, _Float16* __restrict__ Xrb, int M) {
    __shared__ v8h Af[1024];
    MM_STAGE_A_F32(A, ldA)
    MM_WAVE_PROLOG
    MM_COMPUTE_B(Wp0, {
        _Pragma("unroll") for (int i = 0; i < 4; ++i) {
            int gr = grb + i;
            if (gr < M) Xs[(size_t)gr * 128 + col] = (_Float16)c[i];
        }
    })
    MM_COMPUTE_B(Wp0 + 16384, {
        float bc = b1[col];
        _Pragma("unroll") for (int i = 0; i < 4; ++i) {
            int gr = grb + i;
            if (gr < M) Xrb[(size_t)gr * 128 + col] = (_Float16)(c[i] + bc);
        }
    })
}

// fused: S1 = Sin + P@w2 + deg*b2 (written once), then Xs/Xrb = S1 @ w1s/w1r (+b1)
__launch_bounds__(256)
__global__ void k_mm_accxsrb(const _Float16* __restrict__ P, const _Float16* __restrict__ Ww2,
                             const float* __restrict__ b2, const int* __restrict__ deg,
                             const float* __restrict__ Sin, int ldSin,
                             float* __restrict__ Sout,
                             const _Float16* __restrict__ Wp1, const float* __restrict__ b1,
                             _Float16* __restrict__ Xs, _Float16* __restrict__ Xrb, int M) {
    __shared__ v8h Af[1024];
    __shared__ v8h Af2[1024];
    MM_STAGE_A_F16(P)
    MM_WAVE_PROLOG
    _Float16* A2 = (_Float16*)Af2;
    MM_COMPUTE_B(Ww2, {
        float bc = b2[col];
        MM_EXCHANGE_IDX
        _Pragma("unroll") for (int i = 0; i < 4; ++i) {
            int gr = grb + i;
            float sv = 0.f;
            if (gr < M) {
                sv = Sin[(size_t)gr * ldSin + col] + c[i] + bc * (float)deg[gr];
                Sout[(size_t)gr * 128 + col] = sv;
            }
            A2[base + i * 8] = (_Float16)sv;
        }
    })
    __syncthreads();
    MM_RELOAD_A(Af2)
    MM_COMPUTE_B(Wp1, {
        _Pragma("unroll") for (int i = 0; i < 4; ++i) {
            int gr = grb + i;
            if (gr < M) Xs[(size_t)gr * 128 + col] = (_Float16)c[i];
        }
    })
    MM_COMPUTE_B(Wp1 + 16384, {
        float bc = b1[col];
        _Pragma("unroll") for (int i = 0; i < 4; ++i) {
            int gr = grb + i;
            if (gr < M) Xrb[(size_t)gr * 128 + col] = (_Float16)(c[i] + bc);
        }
    })
}

// fused: S2 = Sin + P@w2 + deg*b2 (register-resident); out = S2 + silu(S2@nw1+nb1)@nw2+nb2
__launch_bounds__(256)
__global__ void k_mm_accnode(const _Float16* __restrict__ P, const _Float16* __restrict__ Ww2,
                             const float* __restrict__ b2, const int* __restrict__ deg,
                             const float* __restrict__ Sin,
                             const _Float16* __restrict__ Wn1, const float* __restrict__ nb1,
                             const _Float16* __restrict__ Wn2, const float* __restrict__ nb2,
                             float* __restrict__ out, int M) {
    __shared__ v8h Af[1024];
    __shared__ v8h Af2[1024];
    MM_STAGE_A_F16(P)
    MM_WAVE_PROLOG
    float s2v[8][4];
    _Float16* A2 = (_Float16*)Af2;
    MM_COMPUTE_B(Ww2, {
        float bc = b2[col];
        MM_EXCHANGE_IDX
        _Pragma("unroll") for (int i = 0; i < 4; ++i) {
            int gr = grb + i;
            float sv = 0.f;
            if (gr < M) sv = Sin[(size_t)gr * 128 + col] + c[i] + bc * (float)deg[gr];
            s2v[nt][i] = sv;
            A2[base + i * 8] = (_Float16)sv;
        }
    })
    __syncthreads();
    MM_RELOAD_A(Af2)
    _Float16* A3 = (_Float16*)Af;        // Af free after prolog reads (wave-private writes)
    MM_COMPUTE_B(Wn1, {
        float bc = nb1[col];
        MM_EXCHANGE_IDX
        _Pragma("unroll") for (int i = 0; i < 4; ++i)
            A3[base + i * 8] = (_Float16)silu_f(c[i] + bc);
    })
    __syncthreads();
    MM_RELOAD_A(Af)
    MM_COMPUTE_B(Wn2, {
        float bc = nb2[col];
        _Pragma("unroll") for (int i = 0; i < 4; ++i) {
            int gr = grb + i;
            if (gr < M)
                out[(size_t)gr * NFEAT + col] = s2v[nt][i] + c[i] + bc;
        }
    })
}

// ---------------- edge aggregation: one wave per receiver; scalar payloads;
// gather software pipeline; polynomial silu on packed _Float16 vectors
// (pure v_pk_fma -- NO rcp/exp; transcendental pipe was ~40% of VALU time).
__device__ __forceinline__ v2h silu2_pk(v2h pre) {
    // silu(x) = h*(1+u), h=x/2, u = tanh(clamp(h,+-3)) via odd deg-9 poly:
    //   u = z*(c0 + w*(c1 + w*(c2 + w*(c3 + w*c4)))), w=z^2
    // max |u - tanh| ~= 0.009 (better than the prior Pade's 0.019 @ z=2.1)
    const v2h hp3 = {(_Float16)3.f, (_Float16)3.f};
    const v2h hn3 = {(_Float16)-3.f, (_Float16)-3.f};
    v2h h = pre * (_Float16)0.5f;
    v2h z = __builtin_elementwise_min(__builtin_elementwise_max(h, hn3), hp3);
    v2h w = z * z;
    v2h f = w * (_Float16)0.00033637f + (_Float16)-0.0074935f;
    f = f * w + (_Float16)0.063236f;
    f = f * w + (_Float16)-0.280292f;
    f = f * w + (_Float16)0.988137f;
    v2h u = z * f;
    return h * u + h;
}

__launch_bounds__(256)
__global__ void k_edge(const v2h* __restrict__ Xs, const v2h* __restrict__ Xrb,
                       const float* __restrict__ w1L, const unsigned* __restrict__ epack,
                       const int* __restrict__ rowstart, const int* __restrict__ deg,
                       v2h* __restrict__ P, int N) {
    int wid = (blockIdx.x * blockDim.x + threadIdx.x) >> 6;
    int lane = threadIdx.x & 63;
    if (wid >= N) return;
    int lo = __builtin_amdgcn_readfirstlane(rowstart[wid]);
    int dg = __builtin_amdgcn_readfirstlane(deg[wid]);
    const unsigned* ep = epack + lo;
    v2h xr = Xrb[(size_t)wid * 64 + lane];
    float2 wlf = *(const float2*)(w1L + lane * 2);
    v2h wl = {(_Float16)wlf.x, (_Float16)wlf.y};
    float ax = 0.f, ay = 0.f;
    int k = 0;
    unsigned pc[8];
    v2h xc[8];
    if (dg >= 8) {
#pragma unroll
        for (int u = 0; u < 8; ++u) pc[u] = ep[u];                // uniform -> s_load
#pragma unroll
        for (int u = 0; u < 8; ++u)
            xc[u] = Xs[(size_t)(pc[u] & 0xFFFFu) * 64 + lane];    // SGPR base + lane
    }
    for (; k + 16 <= dg; k += 8) {
        unsigned pn[8];
        v2h xn[8];
#pragma unroll
        for (int u = 0; u < 8; ++u) pn[u] = ep[k + 8 + u];        // prefetch payloads
#pragma unroll
        for (int u = 0; u < 8; ++u)
            xn[u] = Xs[(size_t)(pn[u] & 0xFFFFu) * 64 + lane];    // prefetch gathers
        v2h t2 = {(_Float16)0.f, (_Float16)0.f};
#pragma unroll
        for (int u = 0; u < 8; ++u) {
            _Float16 lv = __builtin_bit_cast(_Float16, (unsigned short)(pc[u] >> 16));
            v2h pre = xc[u] + xr + lv * wl;
            t2 = t2 + silu2_pk(pre);
        }
        ax += (float)t2[0]; ay += (float)t2[1];
#pragma unroll
        for (int u = 0; u < 8; ++u) { pc[u] = pn[u]; xc[u] = xn[u]; }
    }
    if (k + 8 <= dg) {
        v2h t2 = {(_Float16)0.f, (_Float16)0.f};
#pragma unroll
        for (int u = 0; u < 8; ++u) {
            _Float16 lv = __builtin_bit_cast(_Float16, (unsigned short)(pc[u] >> 16));
            v2h pre = xc[u] + xr + lv * wl;
            t2 = t2 + silu2_pk(pre);
        }
        ax += (float)t2[0]; ay += (float)t2[1];
        k += 8;
    }
    for (; k < dg; ++k) {
        unsigned p = ep[k];
        _Float16 lv = __builtin_bit_cast(_Float16, (unsigned short)(p >> 16));
        v2h x = Xs[(size_t)(p & 0xFFFFu) * 64 + lane];
        v2h pre = x + xr + lv * wl;
        v2h s = silu2_pk(pre);
        ax += (float)s[0]; ay += (float)s[1];
    }
    v2h o = {(_Float16)ax, (_Float16)ay};
    P[(size_t)wid * 64 + lane] = o;
}

extern "C" void kernel_launch(void* const* d_in, const int* in_sizes, int n_in,
                              void* d_out, int out_size, void* d_ws, size_t ws_size,
                              hipStream_t stream) {
    const float* h      = (const float*)d_in[0];
    const int*   eidx   = (const int*)d_in[1];
    const float* elen   = (const float*)d_in[2];
    const float* mp_w1  = (const float*)d_in[3];
    const float* mp_b1  = (const float*)d_in[4];
    const float* mp_w2  = (const float*)d_in[5];
    const float* mp_b2  = (const float*)d_in[6];
    const float* nu_w1  = (const float*)d_in[7];
    const float* nu_b1  = (const float*)d_in[8];
    const float* nu_w2  = (const float*)d_in[9];
    const float* nu_b2  = (const float*)d_in[10];
    float* out = (float*)d_out;

    const int N = in_sizes[0] / NFEAT;   // 50000
    const int E = in_sizes[2];           // 1600000
    const int* sender   = eidx;
    const int* receiver = eidx + E;

    char* w = (char*)d_ws;
    auto alloc = [&](size_t bytes) -> char* {
        char* p = w;
        w += (bytes + 255) & ~(size_t)255;
        return p;
    };
    float*    S1    = (float*)alloc((size_t)N * 128 * 4);
    _Float16* Pf    = (_Float16*)alloc((size_t)N * 128 * 2);
    _Float16* Xs16  = (_Float16*)alloc((size_t)N * 128 * 2);
    _Float16* Xrb16 = (_Float16*)alloc((size_t)N * 128 * 2);
    _Float16* Wp    = (_Float16*)alloc((size_t)8 * 16384 * 2);
    int*      br    = (int*)alloc((size_t)NB * CAP * 4);
    unsigned* bsl   = (unsigned*)alloc((size_t)NB * CAP * 4);
    unsigned* epack = (unsigned*)alloc((size_t)NB * CAP * 4);
    int*      deg      = (int*)alloc((size_t)N * 4);
    int*      rowstart = (int*)alloc((size_t)N * 4);
    int*      cnt      = (int*)alloc((size_t)NB * 4);

    (void)hipMemsetAsync(cnt, 0, (size_t)NB * 4, stream);
    k_prep<<<8 + (N + 9) / 10, 256, 0, stream>>>(mp_w1, mp_w2, nu_w1, nu_w2, Wp,
                                                 (const float4*)h, (float4*)out, N);
    const int chunk = 4096;
    cs_bucket<<<(E + chunk - 1) / chunk, 256, 0, stream>>>(receiver, sender, elen, cnt,
                                                           br, bsl, E, chunk);
    cs_csr<<<NB, 256, 0, stream>>>(cnt, br, bsl, deg, rowstart, epack, N);

    const int gb = (N + 63) / 64;            // 782
    const int eb = (N * 64 + 255) / 256;

    // layer 0: Xs/Xrb from h
    k_mm_xsrb2<<<gb, 256, 0, stream>>>(h, NFEAT, Wp, mp_b1, Xs16, Xrb16, N);
    k_edge<<<eb, 256, 0, stream>>>((const v2h*)Xs16, (const v2h*)Xrb16,
                                   mp_w1 + 32768, epack, rowstart, deg, (v2h*)Pf, N);
    // fused: S1 = h + P@w2_l0 + deg*b2_l0 ; Xs/Xrb = S1 @ w1_l1 (+b1_l1)
    k_mm_accxsrb<<<gb, 256, 0, stream>>>(Pf, Wp + (size_t)2 * 16384, mp_b2, deg,
                                         h, NFEAT, S1,
                                         Wp + (size_t)3 * 16384, mp_b1 + 128,
                                         Xs16, Xrb16, N);
    k_edge<<<eb, 256, 0, stream>>>((const v2h*)Xs16, (const v2h*)Xrb16,
                                   mp_w1 + 32896 + 32768, epack, rowstart, deg,
                                   (v2h*)Pf, N);
    // fused: S2 = S1 + P@w2_l1 + deg*b2_l1 (regs) ; out = S2 + MLP(S2)
    k_mm_accnode<<<gb, 256, 0, stream>>>(Pf, Wp + (size_t)5 * 16384, mp_b2 + 128, deg,
                                         S1,
                                         Wp + (size_t)6 * 16384, nu_b1,
                                         Wp + (size_t)7 * 16384, nu_b2,
                                         out, N);
}

// Round 4
// 356.470 us; speedup vs baseline: 1.2239x; 1.0629x over previous
//
#include <hip/hip_runtime.h>
#include <hip/hip_fp16.h>

// FlashACE: 2-layer edge-MLP message passing + node update, N=50000, E=1.6M, HID=128.
//   Xs = S@w1[0:128], Xrb = S@w1[128:256] + b1          (MFMA f16 GEMMs, B direct-global)
//   P[r] = sum_e silu(Xs[s_e] + Xrb[r] + len_e*w1[256]) (edge pass over CSR, scalar path)
//   S += P@w2 + deg*b2 ; out = S + MLP(S)               (MFMA f16 GEMMs)
// Round 14 = Round 13 (k_edge untouched: poly silu, 63us/dispatch) with the
// counting-sort scatter path rebuilt:
//   * br+bsl fused into ONE uint2 array (single 8B store per edge, halves
//     random scatter transactions; cs_csr reads one fused stream)
//   * cs_bucket register-caches recv across its two passes (16-slot static
//     array -> no scratch; saves a full 6.4MB re-read)
//   * cnt memset folded into k_prep (one fewer dispatch/graph node)

#define NFEAT 224
#define RBITS 8                 // receivers per bucket = 256
#define NB 196                  // ceil(50000/256)
#define CAP 10240               // bucket region capacity (mean 8163, sigma ~90)

typedef _Float16 v8h __attribute__((ext_vector_type(8)));
typedef _Float16 v2h __attribute__((ext_vector_type(2)));
typedef float f32x4 __attribute__((ext_vector_type(4)));

#define MFMA16(a, b, c) __builtin_amdgcn_mfma_f32_16x16x32_f16(a, b, c, 0, 0, 0)

__device__ __forceinline__ float silu_f(float x) {
    float e = __expf(-x);
    return x * __builtin_amdgcn_rcpf(1.0f + e);
}

// ---------------- prep: blocks 0..7 pack weights; rest copy h rest-cols -> out
// block 8 additionally zeroes the bucket counters (replaces hipMemsetAsync).
__global__ void k_prep(const float* __restrict__ mp_w1, const float* __restrict__ mp_w2,
                       const float* __restrict__ nu_w1, const float* __restrict__ nu_w2,
                       _Float16* __restrict__ Wp, int* __restrict__ cnt,
                       const float4* __restrict__ h4, float4* __restrict__ out4, int N) {
    if (blockIdx.x < 8) {
        const float* srcs[8] = {
            mp_w1, mp_w1 + 16384, mp_w2,
            mp_w1 + 32896, mp_w1 + 32896 + 16384, mp_w2 + 16384,
            nu_w1, nu_w2
        };
        const float* W = srcs[blockIdx.x];
        _Float16* dst = Wp + (size_t)blockIdx.x * 16384;
        for (int i = 0; i < 8; ++i) {
            int u = threadIdx.x + i * 256;
            int nt = u >> 8;
            int kt = (u >> 6) & 3;
            int lane = u & 63;
            int kb = kt * 32 + (lane >> 4) * 8;
            int n = nt * 16 + (lane & 15);
#pragma unroll
            for (int j = 0; j < 8; ++j)
                dst[(size_t)u * 8 + j] = (_Float16)W[(size_t)(kb + j) * 128 + n];
        }
    } else {
        int b = blockIdx.x - 8;
        int t = threadIdx.x;
        if (b == 0 && t < NB) cnt[t] = 0;
        if (t < 240) {
            int r = b * 10 + t / 24;
            int c = t % 24;
            if (r < N) out4[(size_t)r * 56 + 32 + c] = h4[(size_t)r * 56 + 32 + c];
        }
    }
}

// ---------------- counting sort pass 1: scatter edges into over-allocated buckets
// chunk MUST be 4096 (= 16 * 256) for the static register cache below.
__global__ void cs_bucket(const int* __restrict__ recv, const int* __restrict__ sender,
                          const float* __restrict__ elen, int* __restrict__ cnt,
                          uint2* __restrict__ bp, int E, int chunk) {
    __shared__ int lhist[256];
    __shared__ int lcur[256];
    int t = threadIdx.x;
    int start = blockIdx.x * chunk;
    int end = start + chunk; if (end > E) end = E;
    lhist[t] = 0;
    __syncthreads();
    int rv[16];
#pragma unroll
    for (int j = 0; j < 16; ++j) {
        int i = start + t + j * 256;
        rv[j] = (i < end) ? recv[i] : -1;
        if (rv[j] >= 0) atomicAdd(&lhist[rv[j] >> RBITS], 1);
    }
    __syncthreads();
    if (t < NB) {
        int c = lhist[t];
        lcur[t] = t * CAP + (c ? atomicAdd(&cnt[t], c) : 0);
    }
    __syncthreads();
#pragma unroll
    for (int j = 0; j < 16; ++j) {
        int i = start + t + j * 256;
        if (i < end) {
            int r = rv[j];
            int pos = atomicAdd(&lcur[r >> RBITS], 1);
            unsigned pay = (unsigned)sender[i] |
                           ((unsigned)__half_as_ushort(__float2half_rn(elen[i])) << 16);
            bp[pos] = make_uint2((unsigned)r, pay);
        }
    }
}

// ---------------- counting sort pass 2: one wg per bucket -> CSR + deg/rowstart
__global__ void cs_csr(const int* __restrict__ cnt, const uint2* __restrict__ bp,
                       int* __restrict__ deg, int* __restrict__ rowstart,
                       unsigned* __restrict__ epack, int N) {
    __shared__ int hist[256];
    __shared__ int sh[256];
    __shared__ int lcur[256];
    int t = threadIdx.x;
    int b = blockIdx.x;
    int r0 = b << RBITS;
    int e0 = b * CAP;
    int e1 = e0 + cnt[b];
    hist[t] = 0;
    __syncthreads();
    for (int i = e0 + t; i < e1; i += 256)
        atomicAdd(&hist[(int)(bp[i].x & 255u)], 1);
    __syncthreads();
    sh[t] = hist[t];
    __syncthreads();
    for (int off = 1; off < 256; off <<= 1) {
        int add = (t >= off) ? sh[t - off] : 0;
        __syncthreads();
        sh[t] += add;
        __syncthreads();
    }
    int excl = (t == 0) ? 0 : sh[t - 1];
    lcur[t] = e0 + excl;
    int r = r0 + t;
    if (r < N) { deg[r] = hist[t]; rowstart[r] = e0 + excl; }
    __syncthreads();
    for (int i = e0 + t; i < e1; i += 256) {
        uint2 e = bp[i];
        int pos = atomicAdd(&lcur[(int)(e.x & 255u)], 1);
        epack[pos] = e.y;
    }
}

// ================ MFMA GEMM core: M-tile 64, N=K=128, 256 thr (4 waves) ================
// A staged via LDS. B fragments load DIRECTLY from global (coalesced, L2-hot).

#define MM_STAGE_A_F32(Aptr, ldA)                                           \
    _Pragma("unroll") for (int i = 0; i < 4; ++i) {                         \
        int u = threadIdx.x + i * 256;                                      \
        int r = u >> 4;                                                     \
        int g = u & 15;                                                     \
        int gr = blockIdx.x * 64 + r;                                       \
        float4 x0 = make_float4(0.f, 0.f, 0.f, 0.f);                        \
        float4 x1 = x0;                                                     \
        if (gr < M) {                                                       \
            const float* s_ = (Aptr) + (size_t)gr * (ldA) + g * 8;          \
            x0 = *(const float4*)s_;                                        \
            x1 = *(const float4*)(s_ + 4);                                  \
        }                                                                   \
        v8h hv;                                                             \
        hv[0] = (_Float16)x0.x; hv[1] = (_Float16)x0.y;                     \
        hv[2] = (_Float16)x0.z; hv[3] = (_Float16)x0.w;                     \
        hv[4] = (_Float16)x1.x; hv[5] = (_Float16)x1.y;                     \
        hv[6] = (_Float16)x1.z; hv[7] = (_Float16)x1.w;                     \
        Af[((r >> 4) * 4 + (g >> 2)) * 64 + (g & 3) * 16 + (r & 15)] = hv;  \
    }

#define MM_STAGE_A_F16(Aptr)                                                \
    _Pragma("unroll") for (int i = 0; i < 4; ++i) {                         \
        int u = threadIdx.x + i * 256;                                      \
        int r = u >> 4;                                                     \
        int g = u & 15;                                                     \
        int gr = blockIdx.x * 64 + r;                                       \
        float4 x = make_float4(0.f, 0.f, 0.f, 0.f);                         \
        if (gr < M) x = *(const float4*)((Aptr) + (size_t)gr * 128 + g * 8);\
        *(float4*)&Af[((r >> 4) * 4 + (g >> 2)) * 64 + (g & 3) * 16 + (r & 15)] = x; \
    }

#define MM_WAVE_PROLOG                                                      \
    __syncthreads();                                                        \
    const int wv = threadIdx.x >> 6;                                        \
    const int lane = threadIdx.x & 63;                                      \
    const int q_ = lane >> 4;                                               \
    const int c0_ = lane & 15;                                              \
    v8h a0 = Af[(wv * 4 + 0) * 64 + lane];                                  \
    v8h a1 = Af[(wv * 4 + 1) * 64 + lane];                                  \
    v8h a2 = Af[(wv * 4 + 2) * 64 + lane];                                  \
    v8h a3 = Af[(wv * 4 + 3) * 64 + lane];                                  \
    const int grb = blockIdx.x * 64 + wv * 16 + q_ * 4;

#define MM_RELOAD_A(SRC)                                                    \
    a0 = SRC[(wv * 4 + 0) * 64 + lane];                                     \
    a1 = SRC[(wv * 4 + 1) * 64 + lane];                                     \
    a2 = SRC[(wv * 4 + 2) * 64 + lane];                                     \
    a3 = SRC[(wv * 4 + 3) * 64 + lane];

// B direct-from-global compute pass; epilogue (__VA_ARGS__) sees (c, col, grb, nt, M).
#define MM_COMPUTE_B(WPTR, ...)                                             \
    {                                                                       \
        const v8h* Bp_ = (const v8h*)(WPTR) + lane;                         \
        _Pragma("unroll") for (int nt = 0; nt < 8; ++nt) {                  \
            v8h b0 = Bp_[nt * 256];                                         \
            v8h b1v = Bp_[nt * 256 + 64];                                   \
            v8h b2v = Bp_[nt * 256 + 128];                                  \
            v8h b3v = Bp_[nt * 256 + 192];                                  \
            f32x4 c = {0.f, 0.f, 0.f, 0.f};                                 \
            c = MFMA16(a0, b0, c);                                          \
            c = MFMA16(a1, b1v, c);                                         \
            c = MFMA16(a2, b2v, c);                                         \
            c = MFMA16(a3, b3v, c);                                         \
            const int col = nt * 16 + c0_;                                  \
            __VA_ARGS__                                                     \
        }                                                                   \
    }

// C-frag (c[i] at row grb+i, col) -> f16 A-frag exchange write (wave-private region)
#define MM_EXCHANGE_IDX                                                     \
    int kt = col >> 5;                                                      \
    int o = col & 31;                                                       \
    int qp = o >> 3;                                                        \
    int j = o & 7;                                                          \
    int base = ((wv * 4 + kt) * 64 + qp * 16 + q_ * 4) * 8 + j;

// Xs AND Xrb from one A-stage (layer 0, A = h fp32 ld 224)
__launch_bounds__(256)
__global__ void k_mm_xsrb2(const float* __restrict__ A, int ldA,
                           const _Float16* __restrict__ Wp0, const float* __restrict__ b1,
                           _Float16* __restrict__ Xs, _Float16* __restrict__ Xrb, int M) {
    __shared__ v8h Af[1024];
    MM_STAGE_A_F32(A, ldA)
    MM_WAVE_PROLOG
    MM_COMPUTE_B(Wp0, {
        _Pragma("unroll") for (int i = 0; i < 4; ++i) {
            int gr = grb + i;
            if (gr < M) Xs[(size_t)gr * 128 + col] = (_Float16)c[i];
        }
    })
    MM_COMPUTE_B(Wp0 + 16384, {
        float bc = b1[col];
        _Pragma("unroll") for (int i = 0; i < 4; ++i) {
            int gr = grb + i;
            if (gr < M) Xrb[(size_t)gr * 128 + col] = (_Float16)(c[i] + bc);
        }
    })
}

// fused: S1 = Sin + P@w2 + deg*b2 (written once), then Xs/Xrb = S1 @ w1s/w1r (+b1)
__launch_bounds__(256)
__global__ void k_mm_accxsrb(const _Float16* __restrict__ P, const _Float16* __restrict__ Ww2,
                             const float* __restrict__ b2, const int* __restrict__ deg,
                             const float* __restrict__ Sin, int ldSin,
                             float* __restrict__ Sout,
                             const _Float16* __restrict__ Wp1, const float* __restrict__ b1,
                             _Float16* __restrict__ Xs, _Float16* __restrict__ Xrb, int M) {
    __shared__ v8h Af[1024];
    __shared__ v8h Af2[1024];
    MM_STAGE_A_F16(P)
    MM_WAVE_PROLOG
    _Float16* A2 = (_Float16*)Af2;
    MM_COMPUTE_B(Ww2, {
        float bc = b2[col];
        MM_EXCHANGE_IDX
        _Pragma("unroll") for (int i = 0; i < 4; ++i) {
            int gr = grb + i;
            float sv = 0.f;
            if (gr < M) {
                sv = Sin[(size_t)gr * ldSin + col] + c[i] + bc * (float)deg[gr];
                Sout[(size_t)gr * 128 + col] = sv;
            }
            A2[base + i * 8] = (_Float16)sv;
        }
    })
    __syncthreads();
    MM_RELOAD_A(Af2)
    MM_COMPUTE_B(Wp1, {
        _Pragma("unroll") for (int i = 0; i < 4; ++i) {
            int gr = grb + i;
            if (gr < M) Xs[(size_t)gr * 128 + col] = (_Float16)c[i];
        }
    })
    MM_COMPUTE_B(Wp1 + 16384, {
        float bc = b1[col];
        _Pragma("unroll") for (int i = 0; i < 4; ++i) {
            int gr = grb + i;
            if (gr < M) Xrb[(size_t)gr * 128 + col] = (_Float16)(c[i] + bc);
        }
    })
}

// fused: S2 = Sin + P@w2 + deg*b2 (register-resident); out = S2 + silu(S2@nw1+nb1)@nw2+nb2
__launch_bounds__(256)
__global__ void k_mm_accnode(const _Float16* __restrict__ P, const _Float16* __restrict__ Ww2,
                             const float* __restrict__ b2, const int* __restrict__ deg,
                             const float* __restrict__ Sin,
                             const _Float16* __restrict__ Wn1, const float* __restrict__ nb1,
                             const _Float16* __restrict__ Wn2, const float* __restrict__ nb2,
                             float* __restrict__ out, int M) {
    __shared__ v8h Af[1024];
    __shared__ v8h Af2[1024];
    MM_STAGE_A_F16(P)
    MM_WAVE_PROLOG
    float s2v[8][4];
    _Float16* A2 = (_Float16*)Af2;
    MM_COMPUTE_B(Ww2, {
        float bc = b2[col];
        MM_EXCHANGE_IDX
        _Pragma("unroll") for (int i = 0; i < 4; ++i) {
            int gr = grb + i;
            float sv = 0.f;
            if (gr < M) sv = Sin[(size_t)gr * 128 + col] + c[i] + bc * (float)deg[gr];
            s2v[nt][i] = sv;
            A2[base + i * 8] = (_Float16)sv;
        }
    })
    __syncthreads();
    MM_RELOAD_A(Af2)
    _Float16* A3 = (_Float16*)Af;        // Af free after prolog reads (wave-private writes)
    MM_COMPUTE_B(Wn1, {
        float bc = nb1[col];
        MM_EXCHANGE_IDX
        _Pragma("unroll") for (int i = 0; i < 4; ++i)
            A3[base + i * 8] = (_Float16)silu_f(c[i] + bc);
    })
    __syncthreads();
    MM_RELOAD_A(Af)
    MM_COMPUTE_B(Wn2, {
        float bc = nb2[col];
        _Pragma("unroll") for (int i = 0; i < 4; ++i) {
            int gr = grb + i;
            if (gr < M)
                out[(size_t)gr * NFEAT + col] = s2v[nt][i] + c[i] + bc;
        }
    })
}

// ---------------- edge aggregation: one wave per receiver; scalar payloads;
// gather software pipeline; polynomial silu on packed _Float16 vectors
// (pure v_pk_fma -- NO rcp/exp; transcendental pipe was ~40% of VALU time).
__device__ __forceinline__ v2h silu2_pk(v2h pre) {
    // silu(x) = h*(1+u), h=x/2, u = tanh(clamp(h,+-3)) via odd deg-9 poly:
    //   u = z*(c0 + w*(c1 + w*(c2 + w*(c3 + w*c4)))), w=z^2
    // max |u - tanh| ~= 0.009 (better than the prior Pade's 0.019 @ z=2.1)
    const v2h hp3 = {(_Float16)3.f, (_Float16)3.f};
    const v2h hn3 = {(_Float16)-3.f, (_Float16)-3.f};
    v2h h = pre * (_Float16)0.5f;
    v2h z = __builtin_elementwise_min(__builtin_elementwise_max(h, hn3), hp3);
    v2h w = z * z;
    v2h f = w * (_Float16)0.00033637f + (_Float16)-0.0074935f;
    f = f * w + (_Float16)0.063236f;
    f = f * w + (_Float16)-0.280292f;
    f = f * w + (_Float16)0.988137f;
    v2h u = z * f;
    return h * u + h;
}

__launch_bounds__(256)
__global__ void k_edge(const v2h* __restrict__ Xs, const v2h* __restrict__ Xrb,
                       const float* __restrict__ w1L, const unsigned* __restrict__ epack,
                       const int* __restrict__ rowstart, const int* __restrict__ deg,
                       v2h* __restrict__ P, int N) {
    int wid = (blockIdx.x * blockDim.x + threadIdx.x) >> 6;
    int lane = threadIdx.x & 63;
    if (wid >= N) return;
    int lo = __builtin_amdgcn_readfirstlane(rowstart[wid]);
    int dg = __builtin_amdgcn_readfirstlane(deg[wid]);
    const unsigned* ep = epack + lo;
    v2h xr = Xrb[(size_t)wid * 64 + lane];
    float2 wlf = *(const float2*)(w1L + lane * 2);
    v2h wl = {(_Float16)wlf.x, (_Float16)wlf.y};
    float ax = 0.f, ay = 0.f;
    int k = 0;
    unsigned pc[8];
    v2h xc[8];
    if (dg >= 8) {
#pragma unroll
        for (int u = 0; u < 8; ++u) pc[u] = ep[u];                // uniform -> s_load
#pragma unroll
        for (int u = 0; u < 8; ++u)
            xc[u] = Xs[(size_t)(pc[u] & 0xFFFFu) * 64 + lane];    // SGPR base + lane
    }
    for (; k + 16 <= dg; k += 8) {
        unsigned pn[8];
        v2h xn[8];
#pragma unroll
        for (int u = 0; u < 8; ++u) pn[u] = ep[k + 8 + u];        // prefetch payloads
#pragma unroll
        for (int u = 0; u < 8; ++u)
            xn[u] = Xs[(size_t)(pn[u] & 0xFFFFu) * 64 + lane];    // prefetch gathers
        v2h t2 = {(_Float16)0.f, (_Float16)0.f};
#pragma unroll
        for (int u = 0; u < 8; ++u) {
            _Float16 lv = __builtin_bit_cast(_Float16, (unsigned short)(pc[u] >> 16));
            v2h pre = xc[u] + xr + lv * wl;
            t2 = t2 + silu2_pk(pre);
        }
        ax += (float)t2[0]; ay += (float)t2[1];
#pragma unroll
        for (int u = 0; u < 8; ++u) { pc[u] = pn[u]; xc[u] = xn[u]; }
    }
    if (k + 8 <= dg) {
        v2h t2 = {(_Float16)0.f, (_Float16)0.f};
#pragma unroll
        for (int u = 0; u < 8; ++u) {
            _Float16 lv = __builtin_bit_cast(_Float16, (unsigned short)(pc[u] >> 16));
            v2h pre = xc[u] + xr + lv * wl;
            t2 = t2 + silu2_pk(pre);
        }
        ax += (float)t2[0]; ay += (float)t2[1];
        k += 8;
    }
    for (; k < dg; ++k) {
        unsigned p = ep[k];
        _Float16 lv = __builtin_bit_cast(_Float16, (unsigned short)(p >> 16));
        v2h x = Xs[(size_t)(p & 0xFFFFu) * 64 + lane];
        v2h pre = x + xr + lv * wl;
        v2h s = silu2_pk(pre);
        ax += (float)s[0]; ay += (float)s[1];
    }
    v2h o = {(_Float16)ax, (_Float16)ay};
    P[(size_t)wid * 64 + lane] = o;
}

extern "C" void kernel_launch(void* const* d_in, const int* in_sizes, int n_in,
                              void* d_out, int out_size, void* d_ws, size_t ws_size,
                              hipStream_t stream) {
    const float* h      = (const float*)d_in[0];
    const int*   eidx   = (const int*)d_in[1];
    const float* elen   = (const float*)d_in[2];
    const float* mp_w1  = (const float*)d_in[3];
    const float* mp_b1  = (const float*)d_in[4];
    const float* mp_w2  = (const float*)d_in[5];
    const float* mp_b2  = (const float*)d_in[6];
    const float* nu_w1  = (const float*)d_in[7];
    const float* nu_b1  = (const float*)d_in[8];
    const float* nu_w2  = (const float*)d_in[9];
    const float* nu_b2  = (const float*)d_in[10];
    float* out = (float*)d_out;

    const int N = in_sizes[0] / NFEAT;   // 50000
    const int E = in_sizes[2];           // 1600000
    const int* sender   = eidx;
    const int* receiver = eidx + E;

    char* w = (char*)d_ws;
    auto alloc = [&](size_t bytes) -> char* {
        char* p = w;
        w += (bytes + 255) & ~(size_t)255;
        return p;
    };
    float*    S1    = (float*)alloc((size_t)N * 128 * 4);
    _Float16* Pf    = (_Float16*)alloc((size_t)N * 128 * 2);
    _Float16* Xs16  = (_Float16*)alloc((size_t)N * 128 * 2);
    _Float16* Xrb16 = (_Float16*)alloc((size_t)N * 128 * 2);
    _Float16* Wp    = (_Float16*)alloc((size_t)8 * 16384 * 2);
    uint2*    bp    = (uint2*)alloc((size_t)NB * CAP * 8);
    unsigned* epack = (unsigned*)alloc((size_t)NB * CAP * 4);
    int*      deg      = (int*)alloc((size_t)N * 4);
    int*      rowstart = (int*)alloc((size_t)N * 4);
    int*      cnt      = (int*)alloc((size_t)NB * 4);

    k_prep<<<8 + (N + 9) / 10, 256, 0, stream>>>(mp_w1, mp_w2, nu_w1, nu_w2, Wp, cnt,
                                                 (const float4*)h, (float4*)out, N);
    const int chunk = 4096;                 // MUST stay 16*256 (static reg cache)
    cs_bucket<<<(E + chunk - 1) / chunk, 256, 0, stream>>>(receiver, sender, elen, cnt,
                                                           bp, E, chunk);
    cs_csr<<<NB, 256, 0, stream>>>(cnt, bp, deg, rowstart, epack, N);

    const int gb = (N + 63) / 64;            // 782
    const int eb = (N * 64 + 255) / 256;

    // layer 0: Xs/Xrb from h
    k_mm_xsrb2<<<gb, 256, 0, stream>>>(h, NFEAT, Wp, mp_b1, Xs16, Xrb16, N);
    k_edge<<<eb, 256, 0, stream>>>((const v2h*)Xs16, (const v2h*)Xrb16,
                                   mp_w1 + 32768, epack, rowstart, deg, (v2h*)Pf, N);
    // fused: S1 = h + P@w2_l0 + deg*b2_l0 ; Xs/Xrb = S1 @ w1_l1 (+b1_l1)
    k_mm_accxsrb<<<gb, 256, 0, stream>>>(Pf, Wp + (size_t)2 * 16384, mp_b2, deg,
                                         h, NFEAT, S1,
                                         Wp + (size_t)3 * 16384, mp_b1 + 128,
                                         Xs16, Xrb16, N);
    k_edge<<<eb, 256, 0, stream>>>((const v2h*)Xs16, (const v2h*)Xrb16,
                                   mp_w1 + 32896 + 32768, epack, rowstart, deg,
                                   (v2h*)Pf, N);
    // fused: S2 = S1 + P@w2_l1 + deg*b2_l1 (regs) ; out = S2 + MLP(S2)
    k_mm_accnode<<<gb, 256, 0, stream>>>(Pf, Wp + (size_t)5 * 16384, mp_b2 + 128, deg,
                                         S1,
                                         Wp + (size_t)6 * 16384, nu_b1,
                                         Wp + (size_t)7 * 16384, nu_b2,
                                         out, N);
}

// Round 5
// 338.736 us; speedup vs baseline: 1.2880x; 1.0524x over previous
//
#include <hip/hip_runtime.h>
#include <hip/hip_fp16.h>

// FlashACE: 2-layer edge-MLP message passing + node update, N=50000, E=1.6M, HID=128.
//   Xs = S@w1[0:128], Xrb = S@w1[128:256] + b1          (MFMA f16 GEMMs, B direct-global)
//   P[r] = sum_e silu(Xs[s_e] + Xrb[r] + len_e*w1[256]) (edge pass over CSR, scalar path)
//   S += P@w2 + deg*b2 ; out = S + MLP(S)               (MFMA f16 GEMMs)
// Round 15 = Round 14 with DAG-aware dispatch fusion + the 0.5-fold:
//   * dispatch A = {weight-pack (8 blks) || cs_bucket (391 blks)} -- independent
//   * dispatch B = {cs_csr (196) || layer-0 GEMM (782) || h rest-copy (512)}
//     (CSR build and Xs/Xrb GEMM only join at k_edge#1; single-stream+graph
//      forbids events, so concurrency is expressed via blockIdx partitioning)
//   * Xs/Xrb/wl pre-scaled by 0.5 so k_edge's gather sum IS h=x/2 directly:
//     silu2 drops one pk-mul per edge (~31->29 cy/edge VALU)

#define NFEAT 224
#define RBITS 8                 // receivers per bucket = 256
#define NB 196                  // ceil(50000/256)
#define CAP 10240               // bucket region capacity (mean 8163, sigma ~90)
#define COPYB 512               // grid-stride copy blocks in dispatch B

typedef _Float16 v8h __attribute__((ext_vector_type(8)));
typedef _Float16 v2h __attribute__((ext_vector_type(2)));
typedef float f32x4 __attribute__((ext_vector_type(4)));

#define MFMA16(a, b, c) __builtin_amdgcn_mfma_f32_16x16x32_f16(a, b, c, 0, 0, 0)

__device__ __forceinline__ float silu_f(float x) {
    float e = __expf(-x);
    return x * __builtin_amdgcn_rcpf(1.0f + e);
}

// ---------------- dispatch A: blocks 0..7 pack weights; blocks 8.. bucket-scatter
__global__ void k_packbucket(const float* __restrict__ mp_w1, const float* __restrict__ mp_w2,
                             const float* __restrict__ nu_w1, const float* __restrict__ nu_w2,
                             _Float16* __restrict__ Wp,
                             const int* __restrict__ recv, const int* __restrict__ sender,
                             const float* __restrict__ elen, int* __restrict__ cnt,
                             uint2* __restrict__ bp, int E) {
    __shared__ int lhist[256];
    __shared__ int lcur[256];
    if (blockIdx.x < 8) {
        const float* srcs[8] = {
            mp_w1, mp_w1 + 16384, mp_w2,
            mp_w1 + 32896, mp_w1 + 32896 + 16384, mp_w2 + 16384,
            nu_w1, nu_w2
        };
        const float* W = srcs[blockIdx.x];
        _Float16* dst = Wp + (size_t)blockIdx.x * 16384;
        for (int i = 0; i < 8; ++i) {
            int u = threadIdx.x + i * 256;
            int nt = u >> 8;
            int kt = (u >> 6) & 3;
            int lane = u & 63;
            int kb = kt * 32 + (lane >> 4) * 8;
            int n = nt * 16 + (lane & 15);
#pragma unroll
            for (int j = 0; j < 8; ++j)
                dst[(size_t)u * 8 + j] = (_Float16)W[(size_t)(kb + j) * 128 + n];
        }
        return;
    }
    // counting sort pass 1 (chunk fixed at 4096 = 16*256 for the static reg cache)
    int t = threadIdx.x;
    int start = (blockIdx.x - 8) * 4096;
    int end = start + 4096; if (end > E) end = E;
    lhist[t] = 0;
    __syncthreads();
    int rv[16];
#pragma unroll
    for (int j = 0; j < 16; ++j) {
        int i = start + t + j * 256;
        rv[j] = (i < end) ? recv[i] : -1;
        if (rv[j] >= 0) atomicAdd(&lhist[rv[j] >> RBITS], 1);
    }
    __syncthreads();
    if (t < NB) {
        int c = lhist[t];
        lcur[t] = t * CAP + (c ? atomicAdd(&cnt[t], c) : 0);
    }
    __syncthreads();
#pragma unroll
    for (int j = 0; j < 16; ++j) {
        int i = start + t + j * 256;
        if (i < end) {
            int r = rv[j];
            int pos = atomicAdd(&lcur[r >> RBITS], 1);
            unsigned pay = (unsigned)sender[i] |
                           ((unsigned)__half_as_ushort(__float2half_rn(elen[i])) << 16);
            bp[pos] = make_uint2((unsigned)r, pay);
        }
    }
}

// ================ MFMA GEMM core: M-tile 64, N=K=128, 256 thr (4 waves) ================
// A staged via LDS. B fragments load DIRECTLY from global (coalesced, L2-hot).
// Macros reference local `mm_bx` (block index within the GEMM partition) and `Af`.

#define MM_STAGE_A_F32(Aptr, ldA)                                           \
    _Pragma("unroll") for (int i = 0; i < 4; ++i) {                         \
        int u = threadIdx.x + i * 256;                                      \
        int r = u >> 4;                                                     \
        int g = u & 15;                                                     \
        int gr = mm_bx * 64 + r;                                            \
        float4 x0 = make_float4(0.f, 0.f, 0.f, 0.f);                        \
        float4 x1 = x0;                                                     \
        if (gr < M) {                                                       \
            const float* s_ = (Aptr) + (size_t)gr * (ldA) + g * 8;          \
            x0 = *(const float4*)s_;                                        \
            x1 = *(const float4*)(s_ + 4);                                  \
        }                                                                   \
        v8h hv;                                                             \
        hv[0] = (_Float16)x0.x; hv[1] = (_Float16)x0.y;                     \
        hv[2] = (_Float16)x0.z; hv[3] = (_Float16)x0.w;                     \
        hv[4] = (_Float16)x1.x; hv[5] = (_Float16)x1.y;                     \
        hv[6] = (_Float16)x1.z; hv[7] = (_Float16)x1.w;                     \
        Af[((r >> 4) * 4 + (g >> 2)) * 64 + (g & 3) * 16 + (r & 15)] = hv;  \
    }

#define MM_STAGE_A_F16(Aptr)                                                \
    _Pragma("unroll") for (int i = 0; i < 4; ++i) {                         \
        int u = threadIdx.x + i * 256;                                      \
        int r = u >> 4;                                                     \
        int g = u & 15;                                                     \
        int gr = mm_bx * 64 + r;                                            \
        float4 x = make_float4(0.f, 0.f, 0.f, 0.f);                         \
        if (gr < M) x = *(const float4*)((Aptr) + (size_t)gr * 128 + g * 8);\
        *(float4*)&Af[((r >> 4) * 4 + (g >> 2)) * 64 + (g & 3) * 16 + (r & 15)] = x; \
    }

#define MM_WAVE_PROLOG                                                      \
    __syncthreads();                                                        \
    const int wv = threadIdx.x >> 6;                                        \
    const int lane = threadIdx.x & 63;                                      \
    const int q_ = lane >> 4;                                               \
    const int c0_ = lane & 15;                                              \
    v8h a0 = Af[(wv * 4 + 0) * 64 + lane];                                  \
    v8h a1 = Af[(wv * 4 + 1) * 64 + lane];                                  \
    v8h a2 = Af[(wv * 4 + 2) * 64 + lane];                                  \
    v8h a3 = Af[(wv * 4 + 3) * 64 + lane];                                  \
    const int grb = mm_bx * 64 + wv * 16 + q_ * 4;

#define MM_RELOAD_A(SRC)                                                    \
    a0 = SRC[(wv * 4 + 0) * 64 + lane];                                     \
    a1 = SRC[(wv * 4 + 1) * 64 + lane];                                     \
    a2 = SRC[(wv * 4 + 2) * 64 + lane];                                     \
    a3 = SRC[(wv * 4 + 3) * 64 + lane];

// B direct-from-global compute pass; epilogue (__VA_ARGS__) sees (c, col, grb, nt, M).
#define MM_COMPUTE_B(WPTR, ...)                                             \
    {                                                                       \
        const v8h* Bp_ = (const v8h*)(WPTR) + lane;                         \
        _Pragma("unroll") for (int nt = 0; nt < 8; ++nt) {                  \
            v8h b0 = Bp_[nt * 256];                                         \
            v8h b1v = Bp_[nt * 256 + 64];                                   \
            v8h b2v = Bp_[nt * 256 + 128];                                  \
            v8h b3v = Bp_[nt * 256 + 192];                                  \
            f32x4 c = {0.f, 0.f, 0.f, 0.f};                                 \
            c = MFMA16(a0, b0, c);                                          \
            c = MFMA16(a1, b1v, c);                                         \
            c = MFMA16(a2, b2v, c);                                         \
            c = MFMA16(a3, b3v, c);                                         \
            const int col = nt * 16 + c0_;                                  \
            __VA_ARGS__                                                     \
        }                                                                   \
    }

// C-frag (c[i] at row grb+i, col) -> f16 A-frag exchange write (wave-private region)
#define MM_EXCHANGE_IDX                                                     \
    int kt = col >> 5;                                                      \
    int o = col & 31;                                                       \
    int qp = o >> 3;                                                        \
    int j = o & 7;                                                          \
    int base = ((wv * 4 + kt) * 64 + qp * 16 + q_ * 4) * 8 + j;

// ---------------- dispatch B: blocks [0,NB) csr | [NB, NB+gb) layer-0 GEMM | rest copy
__launch_bounds__(256)
__global__ void k_csr_xsrb_copy(const int* __restrict__ cnt, const uint2* __restrict__ bp,
                                int* __restrict__ deg, int* __restrict__ rowstart,
                                unsigned* __restrict__ epack,
                                const float* __restrict__ A,
                                const _Float16* __restrict__ Wp0, const float* __restrict__ b1,
                                _Float16* __restrict__ Xs, _Float16* __restrict__ Xrb, int M,
                                const float4* __restrict__ h4, float4* __restrict__ out4) {
    __shared__ v8h AfB[1024];            // 16KB: GEMM staging, aliased by csr (3KB)
    const int gb = (M + 63) >> 6;
    if (blockIdx.x < NB) {
        // counting sort pass 2: one block per bucket -> CSR + deg/rowstart
        int* hist = (int*)AfB;
        int* sh = hist + 256;
        int* lcur = sh + 256;
        int t = threadIdx.x;
        int b = blockIdx.x;
        int r0 = b << RBITS;
        int e0 = b * CAP;
        int e1 = e0 + cnt[b];
        hist[t] = 0;
        __syncthreads();
        for (int i = e0 + t; i < e1; i += 256)
            atomicAdd(&hist[(int)(bp[i].x & 255u)], 1);
        __syncthreads();
        sh[t] = hist[t];
        __syncthreads();
        for (int off = 1; off < 256; off <<= 1) {
            int add = (t >= off) ? sh[t - off] : 0;
            __syncthreads();
            sh[t] += add;
            __syncthreads();
        }
        int excl = (t == 0) ? 0 : sh[t - 1];
        lcur[t] = e0 + excl;
        int r = r0 + t;
        if (r < M) { deg[r] = hist[t]; rowstart[r] = e0 + excl; }
        __syncthreads();
        for (int i = e0 + t; i < e1; i += 256) {
            uint2 e = bp[i];
            int pos = atomicAdd(&lcur[(int)(e.x & 255u)], 1);
            epack[pos] = e.y;
        }
    } else if (blockIdx.x < NB + gb) {
        // layer 0 GEMM: Xs/Xrb = h @ w1 (+b1), outputs pre-scaled by 0.5
        v8h* const Af = AfB;
        const int mm_bx = blockIdx.x - NB;
        MM_STAGE_A_F32(A, NFEAT)
        MM_WAVE_PROLOG
        MM_COMPUTE_B(Wp0, {
            _Pragma("unroll") for (int i = 0; i < 4; ++i) {
                int gr = grb + i;
                if (gr < M) Xs[(size_t)gr * 128 + col] = (_Float16)(c[i] * 0.5f);
            }
        })
        MM_COMPUTE_B(Wp0 + 16384, {
            float bc = b1[col];
            _Pragma("unroll") for (int i = 0; i < 4; ++i) {
                int gr = grb + i;
                if (gr < M) Xrb[(size_t)gr * 128 + col] = (_Float16)((c[i] + bc) * 0.5f);
            }
        })
    } else {
        // h rest-cols -> out (independent of everything)
        int bid = blockIdx.x - NB - gb;
        int total = M * 24;
        for (int idx = bid * 256 + threadIdx.x; idx < total; idx += COPYB * 256) {
            int r = idx / 24;
            int c = idx - r * 24;
            out4[(size_t)r * 56 + 32 + c] = h4[(size_t)r * 56 + 32 + c];
        }
    }
}

// fused: S1 = Sin + P@w2 + deg*b2 (written once), then Xs/Xrb = S1 @ w1s/w1r (+b1)
// Xs/Xrb outputs pre-scaled by 0.5 for k_edge.
__launch_bounds__(256)
__global__ void k_mm_accxsrb(const _Float16* __restrict__ P, const _Float16* __restrict__ Ww2,
                             const float* __restrict__ b2, const int* __restrict__ deg,
                             const float* __restrict__ Sin, int ldSin,
                             float* __restrict__ Sout,
                             const _Float16* __restrict__ Wp1, const float* __restrict__ b1,
                             _Float16* __restrict__ Xs, _Float16* __restrict__ Xrb, int M) {
    __shared__ v8h Af[1024];
    __shared__ v8h Af2[1024];
    const int mm_bx = blockIdx.x;
    MM_STAGE_A_F16(P)
    MM_WAVE_PROLOG
    _Float16* A2 = (_Float16*)Af2;
    MM_COMPUTE_B(Ww2, {
        float bc = b2[col];
        MM_EXCHANGE_IDX
        _Pragma("unroll") for (int i = 0; i < 4; ++i) {
            int gr = grb + i;
            float sv = 0.f;
            if (gr < M) {
                sv = Sin[(size_t)gr * ldSin + col] + c[i] + bc * (float)deg[gr];
                Sout[(size_t)gr * 128 + col] = sv;
            }
            A2[base + i * 8] = (_Float16)sv;
        }
    })
    __syncthreads();
    MM_RELOAD_A(Af2)
    MM_COMPUTE_B(Wp1, {
        _Pragma("unroll") for (int i = 0; i < 4; ++i) {
            int gr = grb + i;
            if (gr < M) Xs[(size_t)gr * 128 + col] = (_Float16)(c[i] * 0.5f);
        }
    })
    MM_COMPUTE_B(Wp1 + 16384, {
        float bc = b1[col];
        _Pragma("unroll") for (int i = 0; i < 4; ++i) {
            int gr = grb + i;
            if (gr < M) Xrb[(size_t)gr * 128 + col] = (_Float16)((c[i] + bc) * 0.5f);
        }
    })
}

// fused: S2 = Sin + P@w2 + deg*b2 (register-resident); out = S2 + silu(S2@nw1+nb1)@nw2+nb2
__launch_bounds__(256)
__global__ void k_mm_accnode(const _Float16* __restrict__ P, const _Float16* __restrict__ Ww2,
                             const float* __restrict__ b2, const int* __restrict__ deg,
                             const float* __restrict__ Sin,
                             const _Float16* __restrict__ Wn1, const float* __restrict__ nb1,
                             const _Float16* __restrict__ Wn2, const float* __restrict__ nb2,
                             float* __restrict__ out, int M) {
    __shared__ v8h Af[1024];
    __shared__ v8h Af2[1024];
    const int mm_bx = blockIdx.x;
    MM_STAGE_A_F16(P)
    MM_WAVE_PROLOG
    float s2v[8][4];
    _Float16* A2 = (_Float16*)Af2;
    MM_COMPUTE_B(Ww2, {
        float bc = b2[col];
        MM_EXCHANGE_IDX
        _Pragma("unroll") for (int i = 0; i < 4; ++i) {
            int gr = grb + i;
            float sv = 0.f;
            if (gr < M) sv = Sin[(size_t)gr * 128 + col] + c[i] + bc * (float)deg[gr];
            s2v[nt][i] = sv;
            A2[base + i * 8] = (_Float16)sv;
        }
    })
    __syncthreads();
    MM_RELOAD_A(Af2)
    _Float16* A3 = (_Float16*)Af;        // Af free after prolog reads (wave-private writes)
    MM_COMPUTE_B(Wn1, {
        float bc = nb1[col];
        MM_EXCHANGE_IDX
        _Pragma("unroll") for (int i = 0; i < 4; ++i)
            A3[base + i * 8] = (_Float16)silu_f(c[i] + bc);
    })
    __syncthreads();
    MM_RELOAD_A(Af)
    MM_COMPUTE_B(Wn2, {
        float bc = nb2[col];
        _Pragma("unroll") for (int i = 0; i < 4; ++i) {
            int gr = grb + i;
            if (gr < M)
                out[(size_t)gr * NFEAT + col] = s2v[nt][i] + c[i] + bc;
        }
    })
}

// ---------------- edge aggregation: one wave per receiver; scalar payloads;
// gather software pipeline; polynomial silu on packed _Float16 vectors
// (pure v_pk_fma -- NO rcp/exp). Inputs pre-scaled by 0.5: gather sum IS h=x/2.
__device__ __forceinline__ v2h silu2_pk_h(v2h h) {
    // silu(x) = h*(1+u), u = tanh(clamp(h,+-3)) via odd deg-9 poly:
    //   u = z*(c0 + w*(c1 + w*(c2 + w*(c3 + w*c4)))), w=z^2  (max |err| ~ 0.009)
    const v2h hp3 = {(_Float16)3.f, (_Float16)3.f};
    const v2h hn3 = {(_Float16)-3.f, (_Float16)-3.f};
    v2h z = __builtin_elementwise_min(__builtin_elementwise_max(h, hn3), hp3);
    v2h w = z * z;
    v2h f = w * (_Float16)0.00033637f + (_Float16)-0.0074935f;
    f = f * w + (_Float16)0.063236f;
    f = f * w + (_Float16)-0.280292f;
    f = f * w + (_Float16)0.988137f;
    v2h u = z * f;
    return h * u + h;
}

__launch_bounds__(256)
__global__ void k_edge(const v2h* __restrict__ Xs, const v2h* __restrict__ Xrb,
                       const float* __restrict__ w1L, const unsigned* __restrict__ epack,
                       const int* __restrict__ rowstart, const int* __restrict__ deg,
                       v2h* __restrict__ P, int N) {
    int wid = (blockIdx.x * blockDim.x + threadIdx.x) >> 6;
    int lane = threadIdx.x & 63;
    if (wid >= N) return;
    int lo = __builtin_amdgcn_readfirstlane(rowstart[wid]);
    int dg = __builtin_amdgcn_readfirstlane(deg[wid]);
    const unsigned* ep = epack + lo;
    v2h xr = Xrb[(size_t)wid * 64 + lane];
    float2 wlf = *(const float2*)(w1L + lane * 2);
    v2h wl = {(_Float16)(wlf.x * 0.5f), (_Float16)(wlf.y * 0.5f)};
    float ax = 0.f, ay = 0.f;
    int k = 0;
    unsigned pc[8];
    v2h xc[8];
    if (dg >= 8) {
#pragma unroll
        for (int u = 0; u < 8; ++u) pc[u] = ep[u];                // uniform -> s_load
#pragma unroll
        for (int u = 0; u < 8; ++u)
            xc[u] = Xs[(size_t)(pc[u] & 0xFFFFu) * 64 + lane];    // SGPR base + lane
    }
    for (; k + 16 <= dg; k += 8) {
        unsigned pn[8];
        v2h xn[8];
#pragma unroll
        for (int u = 0; u < 8; ++u) pn[u] = ep[k + 8 + u];        // prefetch payloads
#pragma unroll
        for (int u = 0; u < 8; ++u)
            xn[u] = Xs[(size_t)(pn[u] & 0xFFFFu) * 64 + lane];    // prefetch gathers
        v2h t2 = {(_Float16)0.f, (_Float16)0.f};
#pragma unroll
        for (int u = 0; u < 8; ++u) {
            _Float16 lv = __builtin_bit_cast(_Float16, (unsigned short)(pc[u] >> 16));
            v2h h = xc[u] + xr + lv * wl;
            t2 = t2 + silu2_pk_h(h);
        }
        ax += (float)t2[0]; ay += (float)t2[1];
#pragma unroll
        for (int u = 0; u < 8; ++u) { pc[u] = pn[u]; xc[u] = xn[u]; }
    }
    if (k + 8 <= dg) {
        v2h t2 = {(_Float16)0.f, (_Float16)0.f};
#pragma unroll
        for (int u = 0; u < 8; ++u) {
            _Float16 lv = __builtin_bit_cast(_Float16, (unsigned short)(pc[u] >> 16));
            v2h h = xc[u] + xr + lv * wl;
            t2 = t2 + silu2_pk_h(h);
        }
        ax += (float)t2[0]; ay += (float)t2[1];
        k += 8;
    }
    for (; k < dg; ++k) {
        unsigned p = ep[k];
        _Float16 lv = __builtin_bit_cast(_Float16, (unsigned short)(p >> 16));
        v2h x = Xs[(size_t)(p & 0xFFFFu) * 64 + lane];
        v2h h = x + xr + lv * wl;
        v2h s = silu2_pk_h(h);
        ax += (float)s[0]; ay += (float)s[1];
    }
    v2h o = {(_Float16)ax, (_Float16)ay};
    P[(size_t)wid * 64 + lane] = o;
}

extern "C" void kernel_launch(void* const* d_in, const int* in_sizes, int n_in,
                              void* d_out, int out_size, void* d_ws, size_t ws_size,
                              hipStream_t stream) {
    const float* h      = (const float*)d_in[0];
    const int*   eidx   = (const int*)d_in[1];
    const float* elen   = (const float*)d_in[2];
    const float* mp_w1  = (const float*)d_in[3];
    const float* mp_b1  = (const float*)d_in[4];
    const float* mp_w2  = (const float*)d_in[5];
    const float* mp_b2  = (const float*)d_in[6];
    const float* nu_w1  = (const float*)d_in[7];
    const float* nu_b1  = (const float*)d_in[8];
    const float* nu_w2  = (const float*)d_in[9];
    const float* nu_b2  = (const float*)d_in[10];
    float* out = (float*)d_out;

    const int N = in_sizes[0] / NFEAT;   // 50000
    const int E = in_sizes[2];           // 1600000
    const int* sender   = eidx;
    const int* receiver = eidx + E;

    char* w = (char*)d_ws;
    auto alloc = [&](size_t bytes) -> char* {
        char* p = w;
        w += (bytes + 255) & ~(size_t)255;
        return p;
    };
    float*    S1    = (float*)alloc((size_t)N * 128 * 4);
    _Float16* Pf    = (_Float16*)alloc((size_t)N * 128 * 2);
    _Float16* Xs16  = (_Float16*)alloc((size_t)N * 128 * 2);
    _Float16* Xrb16 = (_Float16*)alloc((size_t)N * 128 * 2);
    _Float16* Wp    = (_Float16*)alloc((size_t)8 * 16384 * 2);
    uint2*    bp    = (uint2*)alloc((size_t)NB * CAP * 8);
    unsigned* epack = (unsigned*)alloc((size_t)NB * CAP * 4);
    int*      deg      = (int*)alloc((size_t)N * 4);
    int*      rowstart = (int*)alloc((size_t)N * 4);
    int*      cnt      = (int*)alloc((size_t)NB * 4);

    (void)hipMemsetAsync(cnt, 0, (size_t)NB * 4, stream);

    const int gb = (N + 63) / 64;            // 782
    const int eb = (N * 64 + 255) / 256;
    const int bb = (E + 4095) / 4096;        // 391

    // A: weight-pack || bucket-scatter (independent)
    k_packbucket<<<8 + bb, 256, 0, stream>>>(mp_w1, mp_w2, nu_w1, nu_w2, Wp,
                                             receiver, sender, elen, cnt, bp, E);
    // B: csr || layer-0 GEMM (Xs/Xrb from h) || h rest-copy (join only at k_edge)
    k_csr_xsrb_copy<<<NB + gb + COPYB, 256, 0, stream>>>(cnt, bp, deg, rowstart, epack,
                                                         h, Wp, mp_b1,
                                                         Xs16, Xrb16, N,
                                                         (const float4*)h, (float4*)out);
    k_edge<<<eb, 256, 0, stream>>>((const v2h*)Xs16, (const v2h*)Xrb16,
                                   mp_w1 + 32768, epack, rowstart, deg, (v2h*)Pf, N);
    // fused: S1 = h + P@w2_l0 + deg*b2_l0 ; Xs/Xrb = S1 @ w1_l1 (+b1_l1)
    k_mm_accxsrb<<<gb, 256, 0, stream>>>(Pf, Wp + (size_t)2 * 16384, mp_b2, deg,
                                         h, NFEAT, S1,
                                         Wp + (size_t)3 * 16384, mp_b1 + 128,
                                         Xs16, Xrb16, N);
    k_edge<<<eb, 256, 0, stream>>>((const v2h*)Xs16, (const v2h*)Xrb16,
                                   mp_w1 + 32896 + 32768, epack, rowstart, deg,
                                   (v2h*)Pf, N);
    // fused: S2 = S1 + P@w2_l1 + deg*b2_l1 (regs) ; out = S2 + MLP(S2)
    k_mm_accnode<<<gb, 256, 0, stream>>>(Pf, Wp + (size_t)5 * 16384, mp_b2 + 128, deg,
                                         S1,
                                         Wp + (size_t)6 * 16384, nu_b1,
                                         Wp + (size_t)7 * 16384, nu_b2,
                                         out, N);
}

// Round 6
// 338.160 us; speedup vs baseline: 1.2902x; 1.0017x over previous
//
#include <hip/hip_runtime.h>
#include <hip/hip_fp16.h>

// FlashACE: 2-layer edge-MLP message passing + node update, N=50000, E=1.6M, HID=128.
//   Xs = S@w1[0:128], Xrb = S@w1[128:256] + b1          (MFMA f16 GEMMs, B direct-global)
//   P[r] = sum_e silu(Xs[s_e] + Xrb[r] + len_e*w1[256]) (edge pass over CSR, scalar path)
//   S += P@w2 + deg*b2 ; out = S + MLP(S)               (MFMA f16 GEMMs)
// Round 16 = Round 15 with k_edge BYTE-IDENTICAL; dark-kernel attack:
//   * accxsrb/accnode rebuilt as 8-wave (512-thr) blocks: nt-loop split across
//     wave pairs (rq=row-quadrant, nh=nt-half) -> 2x resident waves (32/CU) and
//     half the per-wave serial MFMA chain (latency-bound fix, not BW)
//   * f16 residual carry: dispatch-B GEMM stage also stores its f16 A-tile as
//     contiguous H16; accxsrb reads H16 (12.8MB vs 25.6 strided f32) and writes
//     S1 as f16; accnode reads f16 S1. ~38MB less traffic.

#define NFEAT 224
#define RBITS 8                 // receivers per bucket = 256
#define NB 196                  // ceil(50000/256)
#define CAP 10240               // bucket region capacity (mean 8163, sigma ~90)
#define COPYB 512               // grid-stride copy blocks in dispatch B

typedef _Float16 v8h __attribute__((ext_vector_type(8)));
typedef _Float16 v2h __attribute__((ext_vector_type(2)));
typedef float f32x4 __attribute__((ext_vector_type(4)));

#define MFMA16(a, b, c) __builtin_amdgcn_mfma_f32_16x16x32_f16(a, b, c, 0, 0, 0)

__device__ __forceinline__ float silu_f(float x) {
    float e = __expf(-x);
    return x * __builtin_amdgcn_rcpf(1.0f + e);
}

// ---------------- dispatch A: blocks 0..7 pack weights; blocks 8.. bucket-scatter
__global__ void k_packbucket(const float* __restrict__ mp_w1, const float* __restrict__ mp_w2,
                             const float* __restrict__ nu_w1, const float* __restrict__ nu_w2,
                             _Float16* __restrict__ Wp,
                             const int* __restrict__ recv, const int* __restrict__ sender,
                             const float* __restrict__ elen, int* __restrict__ cnt,
                             uint2* __restrict__ bp, int E) {
    __shared__ int lhist[256];
    __shared__ int lcur[256];
    if (blockIdx.x < 8) {
        const float* srcs[8] = {
            mp_w1, mp_w1 + 16384, mp_w2,
            mp_w1 + 32896, mp_w1 + 32896 + 16384, mp_w2 + 16384,
            nu_w1, nu_w2
        };
        const float* W = srcs[blockIdx.x];
        _Float16* dst = Wp + (size_t)blockIdx.x * 16384;
        for (int i = 0; i < 8; ++i) {
            int u = threadIdx.x + i * 256;
            int nt = u >> 8;
            int kt = (u >> 6) & 3;
            int lane = u & 63;
            int kb = kt * 32 + (lane >> 4) * 8;
            int n = nt * 16 + (lane & 15);
#pragma unroll
            for (int j = 0; j < 8; ++j)
                dst[(size_t)u * 8 + j] = (_Float16)W[(size_t)(kb + j) * 128 + n];
        }
        return;
    }
    // counting sort pass 1 (chunk fixed at 4096 = 16*256 for the static reg cache)
    int t = threadIdx.x;
    int start = (blockIdx.x - 8) * 4096;
    int end = start + 4096; if (end > E) end = E;
    lhist[t] = 0;
    __syncthreads();
    int rv[16];
#pragma unroll
    for (int j = 0; j < 16; ++j) {
        int i = start + t + j * 256;
        rv[j] = (i < end) ? recv[i] : -1;
        if (rv[j] >= 0) atomicAdd(&lhist[rv[j] >> RBITS], 1);
    }
    __syncthreads();
    if (t < NB) {
        int c = lhist[t];
        lcur[t] = t * CAP + (c ? atomicAdd(&cnt[t], c) : 0);
    }
    __syncthreads();
#pragma unroll
    for (int j = 0; j < 16; ++j) {
        int i = start + t + j * 256;
        if (i < end) {
            int r = rv[j];
            int pos = atomicAdd(&lcur[r >> RBITS], 1);
            unsigned pay = (unsigned)sender[i] |
                           ((unsigned)__half_as_ushort(__float2half_rn(elen[i])) << 16);
            bp[pos] = make_uint2((unsigned)r, pay);
        }
    }
}

// ================ MFMA GEMM core (4-wave, 256 thr) -- used by dispatch B ================
// A staged via LDS. B fragments load DIRECTLY from global (coalesced, L2-hot).

#define MM_STAGE_A_F32_H16(Aptr, ldA, H16ptr)                               \
    _Pragma("unroll") for (int i = 0; i < 4; ++i) {                         \
        int u = threadIdx.x + i * 256;                                      \
        int r = u >> 4;                                                     \
        int g = u & 15;                                                     \
        int gr = mm_bx * 64 + r;                                            \
        float4 x0 = make_float4(0.f, 0.f, 0.f, 0.f);                        \
        float4 x1 = x0;                                                     \
        if (gr < M) {                                                       \
            const float* s_ = (Aptr) + (size_t)gr * (ldA) + g * 8;          \
            x0 = *(const float4*)s_;                                        \
            x1 = *(const float4*)(s_ + 4);                                  \
        }                                                                   \
        v8h hv;                                                             \
        hv[0] = (_Float16)x0.x; hv[1] = (_Float16)x0.y;                     \
        hv[2] = (_Float16)x0.z; hv[3] = (_Float16)x0.w;                     \
        hv[4] = (_Float16)x1.x; hv[5] = (_Float16)x1.y;                     \
        hv[6] = (_Float16)x1.z; hv[7] = (_Float16)x1.w;                     \
        if (gr < M) *(v8h*)&(H16ptr)[(size_t)gr * 128 + g * 8] = hv;        \
        Af[((r >> 4) * 4 + (g >> 2)) * 64 + (g & 3) * 16 + (r & 15)] = hv;  \
    }

#define MM_WAVE_PROLOG                                                      \
    __syncthreads();                                                        \
    const int wv = threadIdx.x >> 6;                                        \
    const int lane = threadIdx.x & 63;                                      \
    const int q_ = lane >> 4;                                               \
    const int c0_ = lane & 15;                                              \
    v8h a0 = Af[(wv * 4 + 0) * 64 + lane];                                  \
    v8h a1 = Af[(wv * 4 + 1) * 64 + lane];                                  \
    v8h a2 = Af[(wv * 4 + 2) * 64 + lane];                                  \
    v8h a3 = Af[(wv * 4 + 3) * 64 + lane];                                  \
    const int grb = mm_bx * 64 + wv * 16 + q_ * 4;

#define MM_COMPUTE_B(WPTR, ...)                                             \
    {                                                                       \
        const v8h* Bp_ = (const v8h*)(WPTR) + lane;                         \
        _Pragma("unroll") for (int nt = 0; nt < 8; ++nt) {                  \
            v8h b0 = Bp_[nt * 256];                                         \
            v8h b1v = Bp_[nt * 256 + 64];                                   \
            v8h b2v = Bp_[nt * 256 + 128];                                  \
            v8h b3v = Bp_[nt * 256 + 192];                                  \
            f32x4 c = {0.f, 0.f, 0.f, 0.f};                                 \
            c = MFMA16(a0, b0, c);                                          \
            c = MFMA16(a1, b1v, c);                                         \
            c = MFMA16(a2, b2v, c);                                         \
            c = MFMA16(a3, b3v, c);                                         \
            const int col = nt * 16 + c0_;                                  \
            __VA_ARGS__                                                     \
        }                                                                   \
    }

// ================ 8-wave MFMA core (512 thr): nt-loop split across wave pairs =========
// wave wv8 = (nh, rq): rq = row-quadrant (0..3), nh = nt-half (0..1).
// 2x resident waves, half the per-wave MFMA chain vs the 4-wave core.

#define MM8_STAGE_A_F16(Aptr)                                               \
    _Pragma("unroll") for (int i = 0; i < 2; ++i) {                         \
        int u = threadIdx.x + i * 512;                                      \
        int r = u >> 4;                                                     \
        int g = u & 15;                                                     \
        int gr = mm_bx * 64 + r;                                            \
        float4 x = make_float4(0.f, 0.f, 0.f, 0.f);                         \
        if (gr < M) x = *(const float4*)((Aptr) + (size_t)gr * 128 + g * 8);\
        *(float4*)&Af[((r >> 4) * 4 + (g >> 2)) * 64 + (g & 3) * 16 + (r & 15)] = x; \
    }

#define MM8_WAVE_PROLOG                                                     \
    __syncthreads();                                                        \
    const int wv8 = threadIdx.x >> 6;                                       \
    const int rq = wv8 & 3;                                                 \
    const int nh = wv8 >> 2;                                                \
    const int lane = threadIdx.x & 63;                                      \
    const int q_ = lane >> 4;                                               \
    const int c0_ = lane & 15;                                              \
    v8h a0 = Af[(rq * 4 + 0) * 64 + lane];                                  \
    v8h a1 = Af[(rq * 4 + 1) * 64 + lane];                                  \
    v8h a2 = Af[(rq * 4 + 2) * 64 + lane];                                  \
    v8h a3 = Af[(rq * 4 + 3) * 64 + lane];                                  \
    const int grb = mm_bx * 64 + rq * 16 + q_ * 4;

#define MM8_RELOAD_A(SRC)                                                   \
    a0 = SRC[(rq * 4 + 0) * 64 + lane];                                     \
    a1 = SRC[(rq * 4 + 1) * 64 + lane];                                     \
    a2 = SRC[(rq * 4 + 2) * 64 + lane];                                     \
    a3 = SRC[(rq * 4 + 3) * 64 + lane];

#define MM8_COMPUTE_B(WPTR, ...)                                            \
    {                                                                       \
        const v8h* Bp_ = (const v8h*)(WPTR) + lane;                         \
        _Pragma("unroll") for (int ntl = 0; ntl < 4; ++ntl) {               \
            const int nt = nh * 4 + ntl;                                    \
            v8h b0 = Bp_[nt * 256];                                         \
            v8h b1v = Bp_[nt * 256 + 64];                                   \
            v8h b2v = Bp_[nt * 256 + 128];                                  \
            v8h b3v = Bp_[nt * 256 + 192];                                  \
            f32x4 c = {0.f, 0.f, 0.f, 0.f};                                 \
            c = MFMA16(a0, b0, c);                                          \
            c = MFMA16(a1, b1v, c);                                         \
            c = MFMA16(a2, b2v, c);                                         \
            c = MFMA16(a3, b3v, c);                                         \
            const int col = nt * 16 + c0_;                                  \
            __VA_ARGS__                                                     \
        }                                                                   \
    }

// C-frag (c[i] at row grb+i, col) -> f16 A-frag exchange write (disjoint per wave:
// rq fixes the row-group, kt=col>>5 falls in this wave's nh half)
#define MM8_EXCHANGE_IDX                                                    \
    int kt = col >> 5;                                                      \
    int o = col & 31;                                                       \
    int qp = o >> 3;                                                        \
    int j = o & 7;                                                          \
    int base = ((rq * 4 + kt) * 64 + qp * 16 + q_ * 4) * 8 + j;

// ---------------- dispatch B: blocks [0,NB) csr | [NB, NB+gb) layer-0 GEMM | rest copy
__launch_bounds__(256)
__global__ void k_csr_xsrb_copy(const int* __restrict__ cnt, const uint2* __restrict__ bp,
                                int* __restrict__ deg, int* __restrict__ rowstart,
                                unsigned* __restrict__ epack,
                                const float* __restrict__ A,
                                const _Float16* __restrict__ Wp0, const float* __restrict__ b1,
                                _Float16* __restrict__ Xs, _Float16* __restrict__ Xrb,
                                _Float16* __restrict__ H16, int M,
                                const float4* __restrict__ h4, float4* __restrict__ out4) {
    __shared__ v8h AfB[1024];            // 16KB: GEMM staging, aliased by csr (3KB)
    const int gb = (M + 63) >> 6;
    if (blockIdx.x < NB) {
        // counting sort pass 2: one block per bucket -> CSR + deg/rowstart
        int* hist = (int*)AfB;
        int* sh = hist + 256;
        int* lcur = sh + 256;
        int t = threadIdx.x;
        int b = blockIdx.x;
        int r0 = b << RBITS;
        int e0 = b * CAP;
        int e1 = e0 + cnt[b];
        hist[t] = 0;
        __syncthreads();
        for (int i = e0 + t; i < e1; i += 256)
            atomicAdd(&hist[(int)(bp[i].x & 255u)], 1);
        __syncthreads();
        sh[t] = hist[t];
        __syncthreads();
        for (int off = 1; off < 256; off <<= 1) {
            int add = (t >= off) ? sh[t - off] : 0;
            __syncthreads();
            sh[t] += add;
            __syncthreads();
        }
        int excl = (t == 0) ? 0 : sh[t - 1];
        lcur[t] = e0 + excl;
        int r = r0 + t;
        if (r < M) { deg[r] = hist[t]; rowstart[r] = e0 + excl; }
        __syncthreads();
        for (int i = e0 + t; i < e1; i += 256) {
            uint2 e = bp[i];
            int pos = atomicAdd(&lcur[(int)(e.x & 255u)], 1);
            epack[pos] = e.y;
        }
    } else if (blockIdx.x < NB + gb) {
        // layer 0 GEMM: Xs/Xrb = h @ w1 (+b1), outputs pre-scaled by 0.5;
        // also stores the f16 A-tile contiguously as H16 (residual carry for accxsrb)
        v8h* const Af = AfB;
        const int mm_bx = blockIdx.x - NB;
        MM_STAGE_A_F32_H16(A, NFEAT, H16)
        MM_WAVE_PROLOG
        MM_COMPUTE_B(Wp0, {
            _Pragma("unroll") for (int i = 0; i < 4; ++i) {
                int gr = grb + i;
                if (gr < M) Xs[(size_t)gr * 128 + col] = (_Float16)(c[i] * 0.5f);
            }
        })
        MM_COMPUTE_B(Wp0 + 16384, {
            float bc = b1[col];
            _Pragma("unroll") for (int i = 0; i < 4; ++i) {
                int gr = grb + i;
                if (gr < M) Xrb[(size_t)gr * 128 + col] = (_Float16)((c[i] + bc) * 0.5f);
            }
        })
    } else {
        // h rest-cols -> out (independent of everything)
        int bid = blockIdx.x - NB - gb;
        int total = M * 24;
        for (int idx = bid * 256 + threadIdx.x; idx < total; idx += COPYB * 256) {
            int r = idx / 24;
            int c = idx - r * 24;
            out4[(size_t)r * 56 + 32 + c] = h4[(size_t)r * 56 + 32 + c];
        }
    }
}

// fused (8-wave): S1 = H16 + P@w2 + deg*b2 (f16 out), then Xs/Xrb = S1 @ w1s/w1r (+b1)
__launch_bounds__(512)
__global__ void k_mm_accxsrb(const _Float16* __restrict__ P, const _Float16* __restrict__ Ww2,
                             const float* __restrict__ b2, const int* __restrict__ deg,
                             const _Float16* __restrict__ Sin16,
                             _Float16* __restrict__ S1h,
                             const _Float16* __restrict__ Wp1, const float* __restrict__ b1,
                             _Float16* __restrict__ Xs, _Float16* __restrict__ Xrb, int M) {
    __shared__ v8h Af[1024];
    __shared__ v8h Af2[1024];
    const int mm_bx = blockIdx.x;
    MM8_STAGE_A_F16(P)
    MM8_WAVE_PROLOG
    _Float16* A2 = (_Float16*)Af2;
    MM8_COMPUTE_B(Ww2, {
        float bc = b2[col];
        MM8_EXCHANGE_IDX
        _Pragma("unroll") for (int i = 0; i < 4; ++i) {
            int gr = grb + i;
            float sv = 0.f;
            if (gr < M) {
                sv = (float)Sin16[(size_t)gr * 128 + col] + c[i] + bc * (float)deg[gr];
                S1h[(size_t)gr * 128 + col] = (_Float16)sv;
            }
            A2[base + i * 8] = (_Float16)sv;
        }
    })
    __syncthreads();
    MM8_RELOAD_A(Af2)
    MM8_COMPUTE_B(Wp1, {
        _Pragma("unroll") for (int i = 0; i < 4; ++i) {
            int gr = grb + i;
            if (gr < M) Xs[(size_t)gr * 128 + col] = (_Float16)(c[i] * 0.5f);
        }
    })
    MM8_COMPUTE_B(Wp1 + 16384, {
        float bc = b1[col];
        _Pragma("unroll") for (int i = 0; i < 4; ++i) {
            int gr = grb + i;
            if (gr < M) Xrb[(size_t)gr * 128 + col] = (_Float16)((c[i] + bc) * 0.5f);
        }
    })
}

// fused (8-wave): S2 = S1h + P@w2 + deg*b2 (regs); out = S2 + silu(S2@nw1+nb1)@nw2+nb2
__launch_bounds__(512)
__global__ void k_mm_accnode(const _Float16* __restrict__ P, const _Float16* __restrict__ Ww2,
                             const float* __restrict__ b2, const int* __restrict__ deg,
                             const _Float16* __restrict__ Sin16,
                             const _Float16* __restrict__ Wn1, const float* __restrict__ nb1,
                             const _Float16* __restrict__ Wn2, const float* __restrict__ nb2,
                             float* __restrict__ out, int M) {
    __shared__ v8h Af[1024];
    __shared__ v8h Af2[1024];
    const int mm_bx = blockIdx.x;
    MM8_STAGE_A_F16(P)
    MM8_WAVE_PROLOG
    float s2v[4][4];
    _Float16* A2 = (_Float16*)Af2;
    MM8_COMPUTE_B(Ww2, {
        float bc = b2[col];
        MM8_EXCHANGE_IDX
        _Pragma("unroll") for (int i = 0; i < 4; ++i) {
            int gr = grb + i;
            float sv = 0.f;
            if (gr < M) sv = (float)Sin16[(size_t)gr * 128 + col] + c[i] + bc * (float)deg[gr];
            s2v[ntl][i] = sv;
            A2[base + i * 8] = (_Float16)sv;
        }
    })
    __syncthreads();
    MM8_RELOAD_A(Af2)
    _Float16* A3 = (_Float16*)Af;        // Af free after prolog reads (disjoint wave writes)
    MM8_COMPUTE_B(Wn1, {
        float bc = nb1[col];
        MM8_EXCHANGE_IDX
        _Pragma("unroll") for (int i = 0; i < 4; ++i)
            A3[base + i * 8] = (_Float16)silu_f(c[i] + bc);
    })
    __syncthreads();
    MM8_RELOAD_A(Af)
    MM8_COMPUTE_B(Wn2, {
        float bc = nb2[col];
        _Pragma("unroll") for (int i = 0; i < 4; ++i) {
            int gr = grb + i;
            if (gr < M)
                out[(size_t)gr * NFEAT + col] = s2v[ntl][i] + c[i] + bc;
        }
    })
}

// ---------------- edge aggregation (UNCHANGED from round 15): one wave per receiver;
// gather software pipeline; poly silu (pure v_pk_fma). Inputs pre-scaled by 0.5.
__device__ __forceinline__ v2h silu2_pk_h(v2h h) {
    const v2h hp3 = {(_Float16)3.f, (_Float16)3.f};
    const v2h hn3 = {(_Float16)-3.f, (_Float16)-3.f};
    v2h z = __builtin_elementwise_min(__builtin_elementwise_max(h, hn3), hp3);
    v2h w = z * z;
    v2h f = w * (_Float16)0.00033637f + (_Float16)-0.0074935f;
    f = f * w + (_Float16)0.063236f;
    f = f * w + (_Float16)-0.280292f;
    f = f * w + (_Float16)0.988137f;
    v2h u = z * f;
    return h * u + h;
}

__launch_bounds__(256)
__global__ void k_edge(const v2h* __restrict__ Xs, const v2h* __restrict__ Xrb,
                       const float* __restrict__ w1L, const unsigned* __restrict__ epack,
                       const int* __restrict__ rowstart, const int* __restrict__ deg,
                       v2h* __restrict__ P, int N) {
    int wid = (blockIdx.x * blockDim.x + threadIdx.x) >> 6;
    int lane = threadIdx.x & 63;
    if (wid >= N) return;
    int lo = __builtin_amdgcn_readfirstlane(rowstart[wid]);
    int dg = __builtin_amdgcn_readfirstlane(deg[wid]);
    const unsigned* ep = epack + lo;
    v2h xr = Xrb[(size_t)wid * 64 + lane];
    float2 wlf = *(const float2*)(w1L + lane * 2);
    v2h wl = {(_Float16)(wlf.x * 0.5f), (_Float16)(wlf.y * 0.5f)};
    float ax = 0.f, ay = 0.f;
    int k = 0;
    unsigned pc[8];
    v2h xc[8];
    if (dg >= 8) {
#pragma unroll
        for (int u = 0; u < 8; ++u) pc[u] = ep[u];                // uniform -> s_load
#pragma unroll
        for (int u = 0; u < 8; ++u)
            xc[u] = Xs[(size_t)(pc[u] & 0xFFFFu) * 64 + lane];    // SGPR base + lane
    }
    for (; k + 16 <= dg; k += 8) {
        unsigned pn[8];
        v2h xn[8];
#pragma unroll
        for (int u = 0; u < 8; ++u) pn[u] = ep[k + 8 + u];        // prefetch payloads
#pragma unroll
        for (int u = 0; u < 8; ++u)
            xn[u] = Xs[(size_t)(pn[u] & 0xFFFFu) * 64 + lane];    // prefetch gathers
        v2h t2 = {(_Float16)0.f, (_Float16)0.f};
#pragma unroll
        for (int u = 0; u < 8; ++u) {
            _Float16 lv = __builtin_bit_cast(_Float16, (unsigned short)(pc[u] >> 16));
            v2h h = xc[u] + xr + lv * wl;
            t2 = t2 + silu2_pk_h(h);
        }
        ax += (float)t2[0]; ay += (float)t2[1];
#pragma unroll
        for (int u = 0; u < 8; ++u) { pc[u] = pn[u]; xc[u] = xn[u]; }
    }
    if (k + 8 <= dg) {
        v2h t2 = {(_Float16)0.f, (_Float16)0.f};
#pragma unroll
        for (int u = 0; u < 8; ++u) {
            _Float16 lv = __builtin_bit_cast(_Float16, (unsigned short)(pc[u] >> 16));
            v2h h = xc[u] + xr + lv * wl;
            t2 = t2 + silu2_pk_h(h);
        }
        ax += (float)t2[0]; ay += (float)t2[1];
        k += 8;
    }
    for (; k < dg; ++k) {
        unsigned p = ep[k];
        _Float16 lv = __builtin_bit_cast(_Float16, (unsigned short)(p >> 16));
        v2h x = Xs[(size_t)(p & 0xFFFFu) * 64 + lane];
        v2h h = x + xr + lv * wl;
        v2h s = silu2_pk_h(h);
        ax += (float)s[0]; ay += (float)s[1];
    }
    v2h o = {(_Float16)ax, (_Float16)ay};
    P[(size_t)wid * 64 + lane] = o;
}

extern "C" void kernel_launch(void* const* d_in, const int* in_sizes, int n_in,
                              void* d_out, int out_size, void* d_ws, size_t ws_size,
                              hipStream_t stream) {
    const float* h      = (const float*)d_in[0];
    const int*   eidx   = (const int*)d_in[1];
    const float* elen   = (const float*)d_in[2];
    const float* mp_w1  = (const float*)d_in[3];
    const float* mp_b1  = (const float*)d_in[4];
    const float* mp_w2  = (const float*)d_in[5];
    const float* mp_b2  = (const float*)d_in[6];
    const float* nu_w1  = (const float*)d_in[7];
    const float* nu_b1  = (const float*)d_in[8];
    const float* nu_w2  = (const float*)d_in[9];
    const float* nu_b2  = (const float*)d_in[10];
    float* out = (float*)d_out;

    const int N = in_sizes[0] / NFEAT;   // 50000
    const int E = in_sizes[2];           // 1600000
    const int* sender   = eidx;
    const int* receiver = eidx + E;

    char* w = (char*)d_ws;
    auto alloc = [&](size_t bytes) -> char* {
        char* p = w;
        w += (bytes + 255) & ~(size_t)255;
        return p;
    };
    _Float16* S1h   = (_Float16*)alloc((size_t)N * 128 * 2);
    _Float16* H16   = (_Float16*)alloc((size_t)N * 128 * 2);
    _Float16* Pf    = (_Float16*)alloc((size_t)N * 128 * 2);
    _Float16* Xs16  = (_Float16*)alloc((size_t)N * 128 * 2);
    _Float16* Xrb16 = (_Float16*)alloc((size_t)N * 128 * 2);
    _Float16* Wp    = (_Float16*)alloc((size_t)8 * 16384 * 2);
    uint2*    bp    = (uint2*)alloc((size_t)NB * CAP * 8);
    unsigned* epack = (unsigned*)alloc((size_t)NB * CAP * 4);
    int*      deg      = (int*)alloc((size_t)N * 4);
    int*      rowstart = (int*)alloc((size_t)N * 4);
    int*      cnt      = (int*)alloc((size_t)NB * 4);

    (void)hipMemsetAsync(cnt, 0, (size_t)NB * 4, stream);

    const int gb = (N + 63) / 64;            // 782
    const int eb = (N * 64 + 255) / 256;
    const int bb = (E + 4095) / 4096;        // 391

    // A: weight-pack || bucket-scatter (independent)
    k_packbucket<<<8 + bb, 256, 0, stream>>>(mp_w1, mp_w2, nu_w1, nu_w2, Wp,
                                             receiver, sender, elen, cnt, bp, E);
    // B: csr || layer-0 GEMM (Xs/Xrb/H16 from h) || h rest-copy
    k_csr_xsrb_copy<<<NB + gb + COPYB, 256, 0, stream>>>(cnt, bp, deg, rowstart, epack,
                                                         h, Wp, mp_b1,
                                                         Xs16, Xrb16, H16, N,
                                                         (const float4*)h, (float4*)out);
    k_edge<<<eb, 256, 0, stream>>>((const v2h*)Xs16, (const v2h*)Xrb16,
                                   mp_w1 + 32768, epack, rowstart, deg, (v2h*)Pf, N);
    // fused: S1 = H16 + P@w2_l0 + deg*b2_l0 ; Xs/Xrb = S1 @ w1_l1 (+b1_l1)
    k_mm_accxsrb<<<gb, 512, 0, stream>>>(Pf, Wp + (size_t)2 * 16384, mp_b2, deg,
                                         H16, S1h,
                                         Wp + (size_t)3 * 16384, mp_b1 + 128,
                                         Xs16, Xrb16, N);
    k_edge<<<eb, 256, 0, stream>>>((const v2h*)Xs16, (const v2h*)Xrb16,
                                   mp_w1 + 32896 + 32768, epack, rowstart, deg,
                                   (v2h*)Pf, N);
    // fused: S2 = S1h + P@w2_l1 + deg*b2_l1 (regs) ; out = S2 + MLP(S2)
    k_mm_accnode<<<gb, 512, 0, stream>>>(Pf, Wp + (size_t)5 * 16384, mp_b2 + 128, deg,
                                         S1h,
                                         Wp + (size_t)6 * 16384, nu_b1,
                                         Wp + (size_t)7 * 16384, nu_b2,
                                         out, N);
}